// Round 5
// baseline (260.856 us; speedup 1.0000x reference)
//
#include <hip/hip_runtime.h>
#include <math.h>

#define B_ 64
#define N_ 512
#define P_ 256
#define E_ 4096
#define F_ 32
#define H_ 64
#define W_ 8
#define G_ 64
#define RH_ 256

// ---- workspace layout (float offsets) ----
#define X_OFF   0
#define T4_OFF  (X_OFF + N_*B_*F_)       // x:  [n][b][f]
#define T3_OFF  (T4_OFF + N_*B_*H_)      // t4: [n][b][h] (t2 folded in)
#define KB_OFF  (T3_OFF + P_*B_*H_)      // t3: [p][b][h]
#define KW_OFF  (KB_OFF + E_*H_)         // kb: [e][h]
#define YG_OFF  (KW_OFF + E_*B_*W_)      // (kw slot unused now, kept for layout stability)
#define HB_OFF  (YG_OFF + B_*P_*G_)      // yg: [b][p*64+g]
#define RES_OFF (HB_OFF + B_*RH_)        // hbuf: [b][rh]
#define INT_OFF (RES_OFF + 4*B_*G_)      // res4: [pq][b][g]
// int region at INT_OFF: lidx[4096] | ridx[4096] | part_start[512] | pe2[4096 int2]
// r0 partials (256*16384 floats = 16 MB) alias X_OFF.. (x/t4/t3/kb dead after k_eagg)

// ---------------------------------------------------------------------------
// Fused: blocks [0,3072) decode linc/rinc -> lidx/ridx; blocks [3072,3584) conv.
__global__ __launch_bounds__(256) void k_dc(
    const float* __restrict__ linc, const float* __restrict__ rinc,
    int* __restrict__ lidx, int* __restrict__ ridx,
    const float* __restrict__ x1, const float* __restrict__ conv_w,
    const float* __restrict__ conv_b, float* __restrict__ x) {
  __shared__ float wsm[32 * 132];
  __shared__ float xsm[8192];
  int blk = blockIdx.x, t = threadIdx.x;
  if (blk < 3072) {
    int i4 = blk * 256 + t;
    const int L4 = (P_ * E_) / 4;  // 262144
    if (i4 < L4) {
      float4 v = ((const float4*)linc)[i4];
      int i = i4 * 4;
      int p = i >> 12, e = i & 4095;
      if (v.x != 0.0f) lidx[e]     = p;
      if (v.y != 0.0f) lidx[e + 1] = p;
      if (v.z != 0.0f) lidx[e + 2] = p;
      if (v.w != 0.0f) lidx[e + 3] = p;
    } else {
      int j4 = i4 - L4;
      float4 v = ((const float4*)rinc)[j4];
      int j = j4 * 4;
      int e = j >> 9, n = j & 511;
      if (v.x != 0.0f) ridx[e] = n;
      if (v.y != 0.0f) ridx[e] = n + 1;
      if (v.z != 0.0f) ridx[e] = n + 2;
      if (v.w != 0.0f) ridx[e] = n + 3;
    }
    return;
  }
  // ---- grouped conv (K=16, VALID, 1 out pos) + bias + relu -> x[n][b][f] ----
  int n = blk - 3072;
  for (int i = t; i < 1024; i += 256) {
    int f = i >> 5, j = i & 31;
    ((float4*)wsm)[f * 33 + j] = ((const float4*)(conv_w + n * 4096))[i];
  }
  for (int i = t; i < 2048; i += 256) {
    int b = i >> 5, j = i & 31;
    ((float4*)xsm)[i] = ((const float4*)(x1 + b * 65536 + n * 128))[j];
  }
  __syncthreads();
  int f = t & 31, bq = t >> 5;
  float cb = conv_b[n * 32 + f];
  float acc[8];
#pragma unroll
  for (int bi = 0; bi < 8; bi++) acc[bi] = cb;
  const float4* wf4 = (const float4*)wsm + f * 33;
  const float4* xb4 = (const float4*)xsm + bq * 256;
#pragma unroll 4
  for (int k4 = 0; k4 < 32; k4++) {
    float4 wv = wf4[k4];
#pragma unroll
    for (int bi = 0; bi < 8; bi++) {
      float4 xv = xb4[bi * 32 + k4];
      acc[bi] += wv.x * xv.x + wv.y * xv.y + wv.z * xv.z + wv.w * xv.w;
    }
  }
#pragma unroll
  for (int bi = 0; bi < 8; bi++) {
    int b = bq * 8 + bi;
    x[n * 2048 + b * 32 + f] = fmaxf(acc[bi], 0.0f);
  }
}

// blocks [0,512): t4[n][b][h] = x[n]@k4_w^T + x2@k2_w^T
// blocks [512,768): t3[p][b][h] = x[pidx[p]]@k3_w^T
// blocks [768,1792): kb[e][h] = ef[e,:8]@k1_w^T + k1_b
// blocks [1792,1856): hbuf[b][rh] = x2@r1_w^T + r1_b + cap@r2_w^T
// block 1856: counting-sort edges by partition -> part_start, pe2 (e,r) pairs
__global__ __launch_bounds__(256) void k_prep(
    const float* __restrict__ x, const int* __restrict__ pidx,
    const float* __restrict__ k3_w, const float* __restrict__ k4_w,
    const float* __restrict__ x2, const float* __restrict__ k2_w,
    const float* __restrict__ ef, const float* __restrict__ k1_w,
    const float* __restrict__ k1_b,
    const float* __restrict__ r1_w, const float* __restrict__ r1_b,
    const float* __restrict__ r2_w, const float* __restrict__ cap,
    const int* __restrict__ lidx, const int* __restrict__ ridx,
    float* __restrict__ t4, float* __restrict__ t3, float* __restrict__ kb,
    float* __restrict__ hbuf, int* __restrict__ part_start,
    int2* __restrict__ pe2) {
  __shared__ float xsh[2048];
  __shared__ float wsh[64 * 36];
  __shared__ float x2s[512];
  __shared__ float k2s[512];
  __shared__ int cnt[256];
  __shared__ int buf[256];
  __shared__ int cur[256];
  int blk = blockIdx.x, t = threadIdx.x;
  if (blk < 768) {
    bool isT4 = blk < 512;
    int n = isT4 ? blk : pidx[blk - 512];
    const float* wmat = isT4 ? k4_w : k3_w;
    float* outp = isT4 ? (t4 + blk * 4096) : (t3 + (blk - 512) * 4096);
    for (int i = t; i < 512; i += 256) {
      ((float4*)xsh)[i] = ((const float4*)(x + n * 2048))[i];
      int h = i >> 3, j = i & 7;
      ((float4*)wsh)[h * 9 + j] = ((const float4*)wmat)[i];
    }
    if (isT4) {
      for (int i = t; i < 128; i += 256) {
        ((float4*)x2s)[i] = ((const float4*)x2)[i];
        ((float4*)k2s)[i] = ((const float4*)k2_w)[i];
      }
    }
    __syncthreads();
    int h = t & 63, bq = t >> 6;
    float wreg[32];
#pragma unroll
    for (int j = 0; j < 8; j++) {
      float4 v = ((float4*)wsh)[h * 9 + j];
      wreg[4 * j] = v.x; wreg[4 * j + 1] = v.y; wreg[4 * j + 2] = v.z; wreg[4 * j + 3] = v.w;
    }
    float w2[8];
    if (isT4) {
      float4 u = ((float4*)k2s)[h * 2], v = ((float4*)k2s)[h * 2 + 1];
      w2[0] = u.x; w2[1] = u.y; w2[2] = u.z; w2[3] = u.w;
      w2[4] = v.x; w2[5] = v.y; w2[6] = v.z; w2[7] = v.w;
    }
    for (int bi = 0; bi < 16; bi++) {
      int b = bq * 16 + bi;
      float acc = 0.0f;
#pragma unroll
      for (int j = 0; j < 8; j++) {
        float4 xv = ((float4*)xsh)[b * 8 + j];
        acc += xv.x * wreg[4 * j] + xv.y * wreg[4 * j + 1] +
               xv.z * wreg[4 * j + 2] + xv.w * wreg[4 * j + 3];
      }
      if (isT4) {
        float4 u = ((float4*)x2s)[b * 2], v = ((float4*)x2s)[b * 2 + 1];
        acc += u.x * w2[0] + u.y * w2[1] + u.z * w2[2] + u.w * w2[3] +
               v.x * w2[4] + v.y * w2[5] + v.z * w2[6] + v.w * w2[7];
      }
      outp[b * 64 + h] = acc;
    }
  } else if (blk < 1792) {
    int o = (blk - 768) * 256 + t;
    int e = o >> 6, h = o & 63;
    float acc = k1_b[h];
    const float* er = ef + e * 9;
    const float* kr = k1_w + h * 8;
#pragma unroll
    for (int d = 0; d < 8; d++) acc += er[d] * kr[d];
    kb[o] = acc;
  } else if (blk < 1856) {
    int o = (blk - 1792) * 256 + t;
    int rh = o & 255;
    float acc = r1_b[rh];
    const float* xr = x2 + (o >> 8) * 8;
    const float* rr = r1_w + rh * 8;
#pragma unroll
    for (int d = 0; d < 8; d++) acc += xr[d] * rr[d];
    const float* r2r = r2_w + rh * 256;
    for (int p4 = 0; p4 < 64; p4++) {
      float4 cv = ((const float4*)cap)[p4];
      float4 rv = ((const float4*)r2r)[p4];
      acc += cv.x * rv.x + cv.y * rv.y + cv.z * rv.z + cv.w * rv.w;
    }
    hbuf[o] = acc;
  } else {
    // ---- counting sort (single block, 256 threads) ----
    cnt[t] = 0;
    __syncthreads();
    for (int e = t; e < E_; e += 256) atomicAdd(&cnt[lidx[e]], 1);
    __syncthreads();
    buf[t] = cnt[t];
    __syncthreads();
    for (int off = 1; off < 256; off <<= 1) {
      int add = (t >= off) ? buf[t - off] : 0;
      __syncthreads();
      buf[t] += add;
      __syncthreads();
    }
    part_start[t + 1] = buf[t];
    if (t == 0) part_start[0] = 0;
    cur[t] = buf[t] - cnt[t];
    __syncthreads();
    for (int e = t; e < E_; e += 256) {
      int p = lidx[e];
      int pos = atomicAdd(&cur[p], 1);
      pe2[pos] = make_int2(e, ridx[e]);
    }
  }
}

// Fused edge-MLP + aggregation + gc GEMM, one block (512 thr) per partition.
// Two edge-slots (slot = t>>8): slot0 even edges, slot1 odd edges.
// Per-slot laneing: s = t&3 owns h [s*16,s*16+16) for the kern/dot (as round 0);
// after the full butterfly reduce every lane has all 8 pw[w], so the
// accumulate side is re-laned: lane owns ALL 8 w x f-quarter [s*8,s*8+8).
// -> x read per thread/edge = 8 floats (was 32): x traffic 128 MB -> 32 MB,
//    zero redundancy, still fully coalesced (wave reads contiguous 2 KB).
// k5t + t3s in LDS (honest-regalloc shape). Slots merge through fp32
// accS [64][128] in two w-half phases (exact), then gc GEMM epilogue.
__global__ __launch_bounds__(512) void k_eagg(
    const float* __restrict__ x, const float* __restrict__ kb,
    const float* __restrict__ t3, const float* __restrict__ t4,
    const float* __restrict__ k5_w, const float* __restrict__ k5_b,
    const int2* __restrict__ pe2, const int* __restrict__ part_start,
    const float* __restrict__ gc_w, const float* __restrict__ gc_b,
    float* __restrict__ yg) {
  __shared__ float t3s[64 * 68];   // [b][h], stride 68 (bank-spread)
  __shared__ float k5t[4 * 520];   // s-replicated [h][w]
  __shared__ float accS[64 * 128]; // fp32 [b][w-half k], XOR-swizzled (32 KB)
  int p = blockIdx.x, t = threadIdx.x;
  int slot = t >> 8;
  int ts = t & 255;
  int s = ts & 3, b = ts >> 2;
  // stage k5t (512 entries, one per thread) and t3s
  {
    int h = t >> 3, w = t & 7;
    float v = k5_w[w * 64 + h];
#pragma unroll
    for (int qq = 0; qq < 4; qq++) k5t[qq * 520 + t] = v;
  }
  for (int i4 = t; i4 < 1024; i4 += 512) {
    float4 v = ((const float4*)(t3 + p * 4096))[i4];
    *(float4*)(t3s + (i4 >> 4) * 68 + (i4 & 15) * 4) = v;
  }
  __syncthreads();
  const float* kq = k5t + s * 520 + s * 128;  // rows h = s*16..s*16+15
  float kb5[8];
#pragma unroll
  for (int w = 0; w < 8; w++) kb5[w] = k5_b[w];
  const float4* t3p = (const float4*)(t3s + b * 68 + s * 16);
  float acc[64];   // acc[w*8 + j], f = s*8 + j
#pragma unroll
  for (int j = 0; j < 64; j++) acc[j] = 0.0f;
  int s0 = part_start[p], s1 = part_start[p + 1];
  int idx0 = s0 + slot;
  int2 c = make_int2(0, 0);
  if (idx0 < s1) c = pe2[idx0];
  for (int idx = idx0; idx < s1; idx += 2) {
    int n2 = idx + 2;
    int2 cn = (n2 < s1) ? pe2[n2] : c;
    int e = c.x, r = c.y;
    // x f-quarter for this lane (8 floats, coalesced across the wave)
    const float4* xp = (const float4*)(x + r * 2048 + b * 32 + s * 8);
    float4 xq0 = xp[0], xq1 = xp[1];
    const float4* kb4 = (const float4*)(kb + e * 64 + s * 16);
    const float4* t44 = (const float4*)(t4 + r * 4096 + b * 64 + s * 16);
    float lk[16];
#pragma unroll
    for (int j4 = 0; j4 < 4; j4++) {
      float4 a = kb4[j4], cc = t3p[j4], d = t44[j4];
      float v;
      v = a.x + cc.x + d.x; lk[j4 * 4 + 0] = v > 0.0f ? v : 0.02f * v;
      v = a.y + cc.y + d.y; lk[j4 * 4 + 1] = v > 0.0f ? v : 0.02f * v;
      v = a.z + cc.z + d.z; lk[j4 * 4 + 2] = v > 0.0f ? v : 0.02f * v;
      v = a.w + cc.w + d.w; lk[j4 * 4 + 3] = v > 0.0f ? v : 0.02f * v;
    }
    float pw[8] = {0, 0, 0, 0, 0, 0, 0, 0};
#pragma unroll
    for (int j = 0; j < 16; j++) {
      float4 u = *(const float4*)(kq + j * 8);
      float4 v = *(const float4*)(kq + j * 8 + 4);
      float l = lk[j];
      pw[0] += l * u.x; pw[1] += l * u.y; pw[2] += l * u.z; pw[3] += l * u.w;
      pw[4] += l * v.x; pw[5] += l * v.y; pw[6] += l * v.z; pw[7] += l * v.w;
    }
#pragma unroll
    for (int w = 0; w < 8; w++) {  // full butterfly over the 4 s-lanes
      pw[w] += __shfl_xor(pw[w], 1);
      pw[w] += __shfl_xor(pw[w], 2);
    }
    float kv[8];
#pragma unroll
    for (int w = 0; w < 8; w++) kv[w] = fmaxf(pw[w] + kb5[w], 0.0f);
    float xa[8] = {xq0.x, xq0.y, xq0.z, xq0.w, xq1.x, xq1.y, xq1.z, xq1.w};
#pragma unroll
    for (int w = 0; w < 8; w++)
#pragma unroll
      for (int j = 0; j < 8; j++) acc[w * 8 + j] += kv[w] * xa[j];
    c = cn;
  }
  // ---- slot merge + gc GEMM in two w-half phases (fp32 exact) ----
  // k = w*32 + s*8 + j. Phase ph covers w in [ph*4, ph*4+4).
  // khalf4 = w2*8 + s*2 + j4 (float4 col in half-buffer, w2 = w - ph*4);
  // phys4 = (khalf4 & 24) | ((khalf4 ^ b) & 7)   [bank-spread vs b]
  int gq = t >> 6, be = t & 63;
  const float* gwb = gc_w + gq * 8 * 256;
  float ac[8];
#pragma unroll
  for (int i = 0; i < 8; i++) ac[i] = 0.0f;
#pragma unroll
  for (int ph = 0; ph < 2; ph++) {
    if (ph) __syncthreads();  // protect accS while phase-0 reads finish
    if (slot == 0) {
#pragma unroll
      for (int w2 = 0; w2 < 4; w2++)
#pragma unroll
        for (int j4 = 0; j4 < 2; j4++) {
          int khalf4 = w2 * 8 + s * 2 + j4;
          int phys4 = (khalf4 & 24) | ((khalf4 ^ b) & 7);
          int j = (ph * 4 + w2) * 8 + j4 * 4;
          *(float4*)(accS + b * 128 + phys4 * 4) =
              make_float4(acc[j], acc[j + 1], acc[j + 2], acc[j + 3]);
        }
    }
    __syncthreads();
    if (slot == 1) {
#pragma unroll
      for (int w2 = 0; w2 < 4; w2++)
#pragma unroll
        for (int j4 = 0; j4 < 2; j4++) {
          int khalf4 = w2 * 8 + s * 2 + j4;
          int phys4 = (khalf4 & 24) | ((khalf4 ^ b) & 7);
          int j = (ph * 4 + w2) * 8 + j4 * 4;
          float4* ptr = (float4*)(accS + b * 128 + phys4 * 4);
          float4 o = *ptr;
          o.x += acc[j]; o.y += acc[j + 1]; o.z += acc[j + 2]; o.w += acc[j + 3];
          *ptr = o;
        }
    }
    __syncthreads();
    // epilogue partial over this w-half: all 8 waves, wave gq -> g [gq*8,gq*8+8)
    for (int k4h = 0; k4h < 32; k4h++) {
      int phys4 = (k4h & 24) | ((k4h ^ be) & 7);
      float4 av = *(const float4*)(accS + be * 128 + phys4 * 4);
      int w2 = k4h >> 3;
      int k4g = (ph * 4 + w2) * 8 + (k4h & 7);  // global float4 col
#pragma unroll
      for (int i = 0; i < 8; i++) {
        float4 wv = *(const float4*)(gwb + i * 256 + k4g * 4);
        ac[i] += av.x * wv.x + av.y * wv.y + av.z * wv.z + av.w * wv.w;
      }
    }
  }
  float* yp = yg + be * 16384 + p * 64 + gq * 8;
#pragma unroll
  for (int i = 0; i < 8; i++)
    yp[i] = fmaxf(ac[i] + gc_b[gq * 8 + i], 0.0f);
}

// r0 GEMM partials: grid 256 = kc (Kc=64). Block computes full 64b x 256rh tile
// for its k-chunk via outer product; writes part[kc][b][rh].
__global__ __launch_bounds__(256) void k_r0(const float* __restrict__ yg,
    const float* __restrict__ r0_w, float* __restrict__ part) {
  __shared__ float ygs[64 * 68];   // ygT[k][b], row stride 68
  __shared__ float wts[64 * 260];  // wT[k][rh], row stride 260
  int kc = blockIdx.x, t = threadIdx.x;
  int k0 = kc * 64;
  // stage wT: c = t>>4 selects k-group (store lanes spread 32 banks), rr = t&15
  {
    int c = t >> 4, rr = t & 15;
    for (int rd = 0; rd < 16; rd++) {
      int rh = rd * 16 + rr;
      float4 v = *(const float4*)(r0_w + rh * 16384 + k0 + c * 4);
      wts[(4 * c + 0) * 260 + rh] = v.x;
      wts[(4 * c + 1) * 260 + rh] = v.y;
      wts[(4 * c + 2) * 260 + rh] = v.z;
      wts[(4 * c + 3) * 260 + rh] = v.w;
    }
  }
  // stage ygT
  {
    int b = t >> 2, kq = t & 3;
    const float* src = yg + b * 16384 + k0 + kq * 16;
#pragma unroll
    for (int u = 0; u < 4; u++) {
      float4 v = *(const float4*)(src + u * 4);
      int kk = kq * 16 + u * 4;
      ygs[(kk + 0) * 68 + b] = v.x;
      ygs[(kk + 1) * 68 + b] = v.y;
      ygs[(kk + 2) * 68 + b] = v.z;
      ygs[(kk + 3) * 68 + b] = v.w;
    }
  }
  __syncthreads();
  int lane = t & 63, wv = t >> 6;
  int b8 = lane & 7, r8 = lane >> 3;
  const float* yp = ygs + b8 * 8;
  const float* wp = wts + wv * 64 + r8 * 8;
  float acc[8][8];
#pragma unroll
  for (int i = 0; i < 8; i++)
#pragma unroll
    for (int j = 0; j < 8; j++) acc[i][j] = 0.0f;
#pragma unroll 2
  for (int k = 0; k < 64; k++) {
    float4 ya = *(const float4*)(yp + k * 68);
    float4 yb = *(const float4*)(yp + k * 68 + 4);
    float4 wa = *(const float4*)(wp + k * 260);
    float4 wb = *(const float4*)(wp + k * 260 + 4);
    float yv[8] = {ya.x, ya.y, ya.z, ya.w, yb.x, yb.y, yb.z, yb.w};
    float wr[8] = {wa.x, wa.y, wa.z, wa.w, wb.x, wb.y, wb.z, wb.w};
#pragma unroll
    for (int i = 0; i < 8; i++)
#pragma unroll
      for (int j = 0; j < 8; j++) acc[i][j] += yv[i] * wr[j];
  }
  float* pb = part + kc * 16384 + wv * 64 + r8 * 8;
#pragma unroll
  for (int i = 0; i < 8; i++) {
    float4 s0 = make_float4(acc[i][0], acc[i][1], acc[i][2], acc[i][3]);
    float4 s1 = make_float4(acc[i][4], acc[i][5], acc[i][6], acc[i][7]);
    float* pp = pb + (b8 * 8 + i) * 256;
    *(float4*)pp = s0;
    *(float4*)(pp + 4) = s1;
  }
}

// Reduce partials: grid 256 = (kq 4) x (oq 64). hbuf[o] += sum_{kc in kq} part[kc][o]
__global__ __launch_bounds__(256) void k_r0red(const float* __restrict__ part,
    float* __restrict__ hbuf) {
  int blk = blockIdx.x;
  int oq = blk & 63, kq = blk >> 6;
  int o = oq * 256 + threadIdx.x;
  float s = 0.0f;
  const float* pp = part + kq * 64 * 16384 + o;
#pragma unroll 8
  for (int kc = 0; kc < 64; kc++) s += pp[kc * 16384];
  atomicAdd(&hbuf[o], s);
}

// grid 256 = (bb, pq): wt for 64 p's, partial res over those p's -> res4[pq][b][g]
__global__ __launch_bounds__(256) void k_wt_res(const float* __restrict__ hbuf,
    const float* __restrict__ r3_w, const float* __restrict__ r3_b,
    const float* __restrict__ yg, float* __restrict__ res4) {
  __shared__ float hs[256];
  __shared__ float wts[64];
  __shared__ float red[256];
  int blk = blockIdx.x;
  int bb = blk >> 2, pq = blk & 3;
  int t = threadIdx.x;
  float hv = hbuf[bb * 256 + t];
  hs[t] = hv > 0.0f ? hv : 0.01f * hv;
  __syncthreads();
  int pl = t >> 2, c = t & 3;
  int pp = pq * 64 + pl;
  const float4* wrow = (const float4*)(r3_w + pp * 256 + c * 64);
  const float4* h4 = (const float4*)(hs) + c * 16;
  float a = 0.0f;
#pragma unroll
  for (int j = 0; j < 16; j++) {
    float4 w4 = wrow[j], hh = h4[j];
    a += hh.x * w4.x + hh.y * w4.y + hh.z * w4.z + hh.w * w4.w;
  }
  a += __shfl_xor(a, 1);
  a += __shfl_xor(a, 2);
  if (c == 0) wts[pl] = fmaxf(a + r3_b[pp], 0.0f);
  __syncthreads();
  int g = t & 63, ch = t >> 6;
  float r = 0.0f;
  const float* ygp = yg + bb * 16384 + pq * 4096 + g;
#pragma unroll
  for (int pi = 0; pi < 16; pi++) {
    int pl2 = ch * 16 + pi;
    r += wts[pl2] * ygp[pl2 * 64];
  }
  red[t] = r;
  __syncthreads();
  if (t < 64)
    res4[pq * 4096 + bb * 64 + t] = red[t] + red[t + 64] + red[t + 128] + red[t + 192];
}

// z = elu([sum(res4), x2] @ l1_w^T + l1_b); out = z @ l3_w^T + l3_b
__global__ __launch_bounds__(128) void k_final(const float* __restrict__ res4,
    const float* __restrict__ x2, const float* __restrict__ l1_w,
    const float* __restrict__ l1_b, const float* __restrict__ l3_w,
    const float* __restrict__ l3_b, float* __restrict__ out) {
  __shared__ float zs[128];
  int bb = blockIdx.x, t = threadIdx.x;
  float acc = l1_b[t];
  const float* wrow = l1_w + t * 72;
  const float* rr = res4 + bb * 64;
#pragma unroll 8
  for (int j = 0; j < 64; j++) {
    float rv = rr[j] + rr[4096 + j] + rr[8192 + j] + rr[12288 + j];
    acc += rv * wrow[j];
  }
  const float* xr = x2 + bb * 8;
#pragma unroll
  for (int j = 0; j < 8; j++) acc += xr[j] * wrow[64 + j];
  zs[t] = acc > 0.0f ? acc : expm1f(acc);
  __syncthreads();
  if (t < 9) {
    float o = l3_b[t];
    const float* w3 = l3_w + t * 128;
    for (int j = 0; j < 128; j++) o += zs[j] * w3[j];
    out[bb * 9 + t] = o;
  }
}

extern "C" void kernel_launch(void* const* d_in, const int* in_sizes, int n_in,
                              void* d_out, int out_size, void* d_ws, size_t ws_size,
                              hipStream_t stream) {
  (void)in_sizes; (void)n_in; (void)out_size; (void)ws_size;
  const float* x1     = (const float*)d_in[0];
  const float* x2     = (const float*)d_in[1];
  const float* conv_w = (const float*)d_in[2];
  const float* conv_b = (const float*)d_in[3];
  const float* k1_w   = (const float*)d_in[4];
  const float* k1_b   = (const float*)d_in[5];
  const float* k2_w   = (const float*)d_in[6];
  const float* k3_w   = (const float*)d_in[7];
  const float* k4_w   = (const float*)d_in[8];
  const float* k5_w   = (const float*)d_in[9];
  const float* k5_b   = (const float*)d_in[10];
  const float* gc_w   = (const float*)d_in[11];
  const float* gc_b   = (const float*)d_in[12];
  const float* r0_w   = (const float*)d_in[13];
  const float* r1_w   = (const float*)d_in[14];
  const float* r1_b   = (const float*)d_in[15];
  const float* r2_w   = (const float*)d_in[16];
  const float* r3_w   = (const float*)d_in[17];
  const float* r3_b   = (const float*)d_in[18];
  const float* l1_w   = (const float*)d_in[19];
  const float* l1_b   = (const float*)d_in[20];
  const float* l3_w   = (const float*)d_in[21];
  const float* l3_b   = (const float*)d_in[22];
  const float* ef     = (const float*)d_in[23];
  const float* linc   = (const float*)d_in[24];
  const float* rinc   = (const float*)d_in[25];
  const float* cap    = (const float*)d_in[26];
  const int*   pidx   = (const int*)d_in[27];
  float* out = (float*)d_out;

  float* ws   = (float*)d_ws;
  float* xbuf = ws + X_OFF;
  float* t4   = ws + T4_OFF;
  float* t3   = ws + T3_OFF;
  float* kb   = ws + KB_OFF;
  float* yg   = ws + YG_OFF;
  float* hbuf = ws + HB_OFF;
  float* res4 = ws + RES_OFF;
  float* part = ws + X_OFF;   // aliases x/t4/t3/kb (dead after k_eagg)
  int* ib = (int*)(ws + INT_OFF);
  int* lidx = ib;
  int* ridx = ib + 4096;
  int* part_start = ib + 8192;
  int2* pe2 = (int2*)(ib + 8704);   // 4096 int2 = 8192 ints

  hipLaunchKernelGGL(k_dc, dim3(3584), dim3(256), 0, stream,
                     linc, rinc, lidx, ridx, x1, conv_w, conv_b, xbuf);
  hipLaunchKernelGGL(k_prep, dim3(1857), dim3(256), 0, stream,
                     xbuf, pidx, k3_w, k4_w, x2, k2_w, ef, k1_w, k1_b,
                     r1_w, r1_b, r2_w, cap, lidx, ridx,
                     t4, t3, kb, hbuf, part_start, pe2);
  hipLaunchKernelGGL(k_eagg, dim3(256), dim3(512), 0, stream,
                     xbuf, kb, t3, t4, k5_w, k5_b, pe2, part_start,
                     gc_w, gc_b, yg);
  hipLaunchKernelGGL(k_r0, dim3(256), dim3(256), 0, stream, yg, r0_w, part);
  hipLaunchKernelGGL(k_r0red, dim3(256), dim3(256), 0, stream, part, hbuf);
  hipLaunchKernelGGL(k_wt_res, dim3(256), dim3(256), 0, stream, hbuf, r3_w, r3_b, yg, res4);
  hipLaunchKernelGGL(k_final, dim3(64), dim3(128), 0, stream,
                     res4, x2, l1_w, l1_b, l3_w, l3_b, out);
}

// Round 6
// 240.652 us; speedup vs baseline: 1.0840x; 1.0840x over previous
//
#include <hip/hip_runtime.h>
#include <math.h>

#define B_ 64
#define N_ 512
#define P_ 256
#define E_ 4096
#define F_ 32
#define H_ 64
#define W_ 8
#define G_ 64
#define RH_ 256

// ---- workspace layout (float offsets) ----
#define X_OFF   0
#define T4_OFF  (X_OFF + N_*B_*F_)       // x:  [n][b][f]
#define T3_OFF  (T4_OFF + N_*B_*H_)      // t4: [n][b][h] (t2 folded in)
#define KB_OFF  (T3_OFF + P_*B_*H_)      // t3: [p][b][h]
#define KW_OFF  (KB_OFF + E_*H_)         // kb: [e][h]
#define YG_OFF  (KW_OFF + E_*B_*W_)      // kv: [pos][b][w]  (the old unused kw slot)
#define HB_OFF  (YG_OFF + B_*P_*G_)      // yg: [b][p*64+g]
#define RES_OFF (HB_OFF + B_*RH_)        // hbuf: [b][rh]
#define INT_OFF (RES_OFF + 4*B_*G_)      // res4: [pq][b][g]
// int region at INT_OFF: lidx[4096] | ridx[4096] | part_start[512] | pe2[4096 int2]
// r0 partials (256*16384 floats = 16 MB) alias X_OFF..T3 (x/t4/t3 dead after k_agg;
// kv lives at KW_OFF which the part region does NOT overlap)

// ---------------------------------------------------------------------------
// Fused: blocks [0,3072) decode linc/rinc -> lidx/ridx; blocks [3072,3584) conv.
__global__ __launch_bounds__(256) void k_dc(
    const float* __restrict__ linc, const float* __restrict__ rinc,
    int* __restrict__ lidx, int* __restrict__ ridx,
    const float* __restrict__ x1, const float* __restrict__ conv_w,
    const float* __restrict__ conv_b, float* __restrict__ x) {
  __shared__ float wsm[32 * 132];
  __shared__ float xsm[8192];
  int blk = blockIdx.x, t = threadIdx.x;
  if (blk < 3072) {
    int i4 = blk * 256 + t;
    const int L4 = (P_ * E_) / 4;  // 262144
    if (i4 < L4) {
      float4 v = ((const float4*)linc)[i4];
      int i = i4 * 4;
      int p = i >> 12, e = i & 4095;
      if (v.x != 0.0f) lidx[e]     = p;
      if (v.y != 0.0f) lidx[e + 1] = p;
      if (v.z != 0.0f) lidx[e + 2] = p;
      if (v.w != 0.0f) lidx[e + 3] = p;
    } else {
      int j4 = i4 - L4;
      float4 v = ((const float4*)rinc)[j4];
      int j = j4 * 4;
      int e = j >> 9, n = j & 511;
      if (v.x != 0.0f) ridx[e] = n;
      if (v.y != 0.0f) ridx[e] = n + 1;
      if (v.z != 0.0f) ridx[e] = n + 2;
      if (v.w != 0.0f) ridx[e] = n + 3;
    }
    return;
  }
  // ---- grouped conv (K=16, VALID, 1 out pos) + bias + relu -> x[n][b][f] ----
  int n = blk - 3072;
  for (int i = t; i < 1024; i += 256) {
    int f = i >> 5, j = i & 31;
    ((float4*)wsm)[f * 33 + j] = ((const float4*)(conv_w + n * 4096))[i];
  }
  for (int i = t; i < 2048; i += 256) {
    int b = i >> 5, j = i & 31;
    ((float4*)xsm)[i] = ((const float4*)(x1 + b * 65536 + n * 128))[j];
  }
  __syncthreads();
  int f = t & 31, bq = t >> 5;
  float cb = conv_b[n * 32 + f];
  float acc[8];
#pragma unroll
  for (int bi = 0; bi < 8; bi++) acc[bi] = cb;
  const float4* wf4 = (const float4*)wsm + f * 33;
  const float4* xb4 = (const float4*)xsm + bq * 256;
#pragma unroll 4
  for (int k4 = 0; k4 < 32; k4++) {
    float4 wv = wf4[k4];
#pragma unroll
    for (int bi = 0; bi < 8; bi++) {
      float4 xv = xb4[bi * 32 + k4];
      acc[bi] += wv.x * xv.x + wv.y * xv.y + wv.z * xv.z + wv.w * xv.w;
    }
  }
#pragma unroll
  for (int bi = 0; bi < 8; bi++) {
    int b = bq * 8 + bi;
    x[n * 2048 + b * 32 + f] = fmaxf(acc[bi], 0.0f);
  }
}

// blocks [0,512): t4[n][b][h] = x[n]@k4_w^T + x2@k2_w^T
// blocks [512,768): t3[p][b][h] = x[pidx[p]]@k3_w^T
// blocks [768,1792): kb[e][h] = ef[e,:8]@k1_w^T + k1_b
// blocks [1792,1856): hbuf[b][rh] = x2@r1_w^T + r1_b + cap@r2_w^T
// block 1856: counting-sort edges by partition -> part_start, pe2 packed
//             pe2[pos] = (e | p<<16, r)
__global__ __launch_bounds__(256) void k_prep(
    const float* __restrict__ x, const int* __restrict__ pidx,
    const float* __restrict__ k3_w, const float* __restrict__ k4_w,
    const float* __restrict__ x2, const float* __restrict__ k2_w,
    const float* __restrict__ ef, const float* __restrict__ k1_w,
    const float* __restrict__ k1_b,
    const float* __restrict__ r1_w, const float* __restrict__ r1_b,
    const float* __restrict__ r2_w, const float* __restrict__ cap,
    const int* __restrict__ lidx, const int* __restrict__ ridx,
    float* __restrict__ t4, float* __restrict__ t3, float* __restrict__ kb,
    float* __restrict__ hbuf, int* __restrict__ part_start,
    int2* __restrict__ pe2) {
  __shared__ float xsh[2048];
  __shared__ float wsh[64 * 36];
  __shared__ float x2s[512];
  __shared__ float k2s[512];
  __shared__ int cnt[256];
  __shared__ int buf[256];
  __shared__ int cur[256];
  int blk = blockIdx.x, t = threadIdx.x;
  if (blk < 768) {
    bool isT4 = blk < 512;
    int n = isT4 ? blk : pidx[blk - 512];
    const float* wmat = isT4 ? k4_w : k3_w;
    float* outp = isT4 ? (t4 + blk * 4096) : (t3 + (blk - 512) * 4096);
    for (int i = t; i < 512; i += 256) {
      ((float4*)xsh)[i] = ((const float4*)(x + n * 2048))[i];
      int h = i >> 3, j = i & 7;
      ((float4*)wsh)[h * 9 + j] = ((const float4*)wmat)[i];
    }
    if (isT4) {
      for (int i = t; i < 128; i += 256) {
        ((float4*)x2s)[i] = ((const float4*)x2)[i];
        ((float4*)k2s)[i] = ((const float4*)k2_w)[i];
      }
    }
    __syncthreads();
    int h = t & 63, bq = t >> 6;
    float wreg[32];
#pragma unroll
    for (int j = 0; j < 8; j++) {
      float4 v = ((float4*)wsh)[h * 9 + j];
      wreg[4 * j] = v.x; wreg[4 * j + 1] = v.y; wreg[4 * j + 2] = v.z; wreg[4 * j + 3] = v.w;
    }
    float w2[8];
    if (isT4) {
      float4 u = ((float4*)k2s)[h * 2], v = ((float4*)k2s)[h * 2 + 1];
      w2[0] = u.x; w2[1] = u.y; w2[2] = u.z; w2[3] = u.w;
      w2[4] = v.x; w2[5] = v.y; w2[6] = v.z; w2[7] = v.w;
    }
    for (int bi = 0; bi < 16; bi++) {
      int b = bq * 16 + bi;
      float acc = 0.0f;
#pragma unroll
      for (int j = 0; j < 8; j++) {
        float4 xv = ((float4*)xsh)[b * 8 + j];
        acc += xv.x * wreg[4 * j] + xv.y * wreg[4 * j + 1] +
               xv.z * wreg[4 * j + 2] + xv.w * wreg[4 * j + 3];
      }
      if (isT4) {
        float4 u = ((float4*)x2s)[b * 2], v = ((float4*)x2s)[b * 2 + 1];
        acc += u.x * w2[0] + u.y * w2[1] + u.z * w2[2] + u.w * w2[3] +
               v.x * w2[4] + v.y * w2[5] + v.z * w2[6] + v.w * w2[7];
      }
      outp[b * 64 + h] = acc;
    }
  } else if (blk < 1792) {
    int o = (blk - 768) * 256 + t;
    int e = o >> 6, h = o & 63;
    float acc = k1_b[h];
    const float* er = ef + e * 9;
    const float* kr = k1_w + h * 8;
#pragma unroll
    for (int d = 0; d < 8; d++) acc += er[d] * kr[d];
    kb[o] = acc;
  } else if (blk < 1856) {
    int o = (blk - 1792) * 256 + t;
    int rh = o & 255;
    float acc = r1_b[rh];
    const float* xr = x2 + (o >> 8) * 8;
    const float* rr = r1_w + rh * 8;
#pragma unroll
    for (int d = 0; d < 8; d++) acc += xr[d] * rr[d];
    const float* r2r = r2_w + rh * 256;
    for (int p4 = 0; p4 < 64; p4++) {
      float4 cv = ((const float4*)cap)[p4];
      float4 rv = ((const float4*)r2r)[p4];
      acc += cv.x * rv.x + cv.y * rv.y + cv.z * rv.z + cv.w * rv.w;
    }
    hbuf[o] = acc;
  } else {
    // ---- counting sort (single block, 256 threads) ----
    cnt[t] = 0;
    __syncthreads();
    for (int e = t; e < E_; e += 256) atomicAdd(&cnt[lidx[e]], 1);
    __syncthreads();
    buf[t] = cnt[t];
    __syncthreads();
    for (int off = 1; off < 256; off <<= 1) {
      int add = (t >= off) ? buf[t - off] : 0;
      __syncthreads();
      buf[t] += add;
      __syncthreads();
    }
    part_start[t + 1] = buf[t];
    if (t == 0) part_start[0] = 0;
    cur[t] = buf[t] - cnt[t];
    __syncthreads();
    for (int e = t; e < E_; e += 256) {
      int p = lidx[e];
      int pos = atomicAdd(&cur[p], 1);
      pe2[pos] = make_int2(e | (p << 16), ridx[e]);
    }
  }
}

// Per-edge kernel MLP: one block per sorted edge position (grid 4096).
// kv[pos][b][w] = relu(sum_h leaky(kb[e,h]+t3[p,b,h]+t4[r,b,h]) * k5[w,h] + b5[w])
// All reads coalesced (4KB wave reads of t3/t4 rows). XCD-bijective swizzle keeps
// consecutive positions (same partition -> same t3 row) on one XCD's L2.
__global__ __launch_bounds__(256) void k_kern(
    const float* __restrict__ kb, const float* __restrict__ t3,
    const float* __restrict__ t4, const float* __restrict__ k5_w,
    const float* __restrict__ k5_b, const int2* __restrict__ pe2,
    float* __restrict__ kv) {
  __shared__ float k5t[4 * 520];   // s-replicated [h][w]
  int bid = blockIdx.x;
  int pos = (bid & 7) * 512 + (bid >> 3);   // 4096 % 8 == 0 -> bijective
  int t = threadIdx.x;
  for (int i = t; i < 512; i += 256) {
    int h = i >> 3, w = i & 7;
    float v = k5_w[w * 64 + h];
#pragma unroll
    for (int qq = 0; qq < 4; qq++) k5t[qq * 520 + i] = v;
  }
  int2 c = pe2[pos];
  int e = c.x & 0xffff, p = c.x >> 16, r = c.y;
  int s = t & 3, b = t >> 2;
  __syncthreads();
  const float* kq = k5t + s * 520 + s * 128;  // rows h = s*16..s*16+15
  const float4* kb4 = (const float4*)(kb + e * 64 + s * 16);
  const float4* t34 = (const float4*)(t3 + p * 4096 + b * 64 + s * 16);
  const float4* t44 = (const float4*)(t4 + r * 4096 + b * 64 + s * 16);
  float lk[16];
#pragma unroll
  for (int j4 = 0; j4 < 4; j4++) {
    float4 a = kb4[j4], cc = t34[j4], d = t44[j4];
    float v;
    v = a.x + cc.x + d.x; lk[j4 * 4 + 0] = v > 0.0f ? v : 0.02f * v;
    v = a.y + cc.y + d.y; lk[j4 * 4 + 1] = v > 0.0f ? v : 0.02f * v;
    v = a.z + cc.z + d.z; lk[j4 * 4 + 2] = v > 0.0f ? v : 0.02f * v;
    v = a.w + cc.w + d.w; lk[j4 * 4 + 3] = v > 0.0f ? v : 0.02f * v;
  }
  float pw[8] = {0, 0, 0, 0, 0, 0, 0, 0};
#pragma unroll
  for (int j = 0; j < 16; j++) {
    float4 u = *(const float4*)(kq + j * 8);
    float4 v = *(const float4*)(kq + j * 8 + 4);
    float l = lk[j];
    pw[0] += l * u.x; pw[1] += l * u.y; pw[2] += l * u.z; pw[3] += l * u.w;
    pw[4] += l * v.x; pw[5] += l * v.y; pw[6] += l * v.z; pw[7] += l * v.w;
  }
#pragma unroll
  for (int w = 0; w < 8; w++) {  // reduce over the 4 s-lanes
    pw[w] += __shfl_xor(pw[w], 1);
    pw[w] += __shfl_xor(pw[w], 2);
  }
  float2 o;
  o.x = fmaxf(pw[2 * s] + k5_b[2 * s], 0.0f);
  o.y = fmaxf(pw[2 * s + 1] + k5_b[2 * s + 1], 0.0f);
  // lane (b,s) -> float2 at b*8+2s: wave writes contiguous 512B
  *(float2*)(kv + pos * 512 + b * 8 + 2 * s) = o;
}

// Aggregation + gc GEMM, one block (512 thr) per partition, 2 edge-slots.
// Main loop per edge: kv read (contiguous) + x gather + 64 FMA. No shfl/LDS.
// gc_w staged once into LDS (epilogue reads are uniform -> free broadcasts).
// Slots merge through fp32 accS in two w-half phases (exact), then gc GEMM.
__global__ __launch_bounds__(512, 2) void k_agg(
    const float* __restrict__ x, const float* __restrict__ kv,
    const int2* __restrict__ pe2, const int* __restrict__ part_start,
    const float* __restrict__ gc_w, const float* __restrict__ gc_b,
    float* __restrict__ yg) {
  __shared__ float accS[64 * 128]; // fp32 [b][w-half k], XOR-swizzled (32 KB)
  __shared__ float gcS[64 * 256];  // gc_w staged (64 KB)
  int p = blockIdx.x, t = threadIdx.x;
  int slot = t >> 8;
  int ts = t & 255;
  int s = ts & 3, b = ts >> 2;
  for (int i4 = t; i4 < 4096; i4 += 512)
    ((float4*)gcS)[i4] = ((const float4*)gc_w)[i4];
  float acc[64];   // acc[w*8 + j], f = s*8 + j
#pragma unroll
  for (int j = 0; j < 64; j++) acc[j] = 0.0f;
  int s0 = part_start[p], s1 = part_start[p + 1];
  int idx = s0 + slot;
  int r = (idx < s1) ? pe2[idx].y : 0;
  for (; idx < s1; idx += 2) {
    int rn = (idx + 2 < s1) ? pe2[idx + 2].y : 0;
    const float4* kvp = (const float4*)(kv + idx * 512 + b * 8);
    float4 ka = kvp[0], kc = kvp[1];
    const float4* xp = (const float4*)(x + r * 2048 + b * 32 + s * 8);
    float4 xq0 = xp[0], xq1 = xp[1];
    float kw[8] = {ka.x, ka.y, ka.z, ka.w, kc.x, kc.y, kc.z, kc.w};
    float xa[8] = {xq0.x, xq0.y, xq0.z, xq0.w, xq1.x, xq1.y, xq1.z, xq1.w};
#pragma unroll
    for (int w = 0; w < 8; w++)
#pragma unroll
      for (int j = 0; j < 8; j++) acc[w * 8 + j] += kw[w] * xa[j];
    r = rn;
  }
  // ---- slot merge + gc GEMM in two w-half phases (fp32 exact) ----
  // k = w*32 + s*8 + j. Phase ph covers w in [ph*4, ph*4+4).
  // khalf4 = w2*8 + s*2 + j4; phys4 = (khalf4 & 24) | ((khalf4 ^ b) & 7)
  int gq = t >> 6, be = t & 63;
  float ac[8];
#pragma unroll
  for (int i = 0; i < 8; i++) ac[i] = 0.0f;
#pragma unroll
  for (int ph = 0; ph < 2; ph++) {
    if (ph) __syncthreads();  // protect accS while phase-0 reads finish
    if (slot == 0) {
#pragma unroll
      for (int w2 = 0; w2 < 4; w2++)
#pragma unroll
        for (int j4 = 0; j4 < 2; j4++) {
          int khalf4 = w2 * 8 + s * 2 + j4;
          int phys4 = (khalf4 & 24) | ((khalf4 ^ b) & 7);
          int j = (ph * 4 + w2) * 8 + j4 * 4;
          *(float4*)(accS + b * 128 + phys4 * 4) =
              make_float4(acc[j], acc[j + 1], acc[j + 2], acc[j + 3]);
        }
    }
    __syncthreads();
    if (slot == 1) {
#pragma unroll
      for (int w2 = 0; w2 < 4; w2++)
#pragma unroll
        for (int j4 = 0; j4 < 2; j4++) {
          int khalf4 = w2 * 8 + s * 2 + j4;
          int phys4 = (khalf4 & 24) | ((khalf4 ^ b) & 7);
          int j = (ph * 4 + w2) * 8 + j4 * 4;
          float4* ptr = (float4*)(accS + b * 128 + phys4 * 4);
          float4 o = *ptr;
          o.x += acc[j]; o.y += acc[j + 1]; o.z += acc[j + 2]; o.w += acc[j + 3];
          *ptr = o;
        }
    }
    __syncthreads();
    // epilogue partial over this w-half: wave gq -> g [gq*8,gq*8+8), lane = b row
    for (int k4h = 0; k4h < 32; k4h++) {
      int phys4 = (k4h & 24) | ((k4h ^ be) & 7);
      float4 av = *(const float4*)(accS + be * 128 + phys4 * 4);
      int w2 = k4h >> 3;
      int k4g = (ph * 4 + w2) * 8 + (k4h & 7);  // global float4 col
#pragma unroll
      for (int i = 0; i < 8; i++) {
        float4 wv = *(const float4*)(gcS + (gq * 8 + i) * 256 + k4g * 4);
        ac[i] += av.x * wv.x + av.y * wv.y + av.z * wv.z + av.w * wv.w;
      }
    }
  }
  float* yp = yg + be * 16384 + p * 64 + gq * 8;
#pragma unroll
  for (int i = 0; i < 8; i++)
    yp[i] = fmaxf(ac[i] + gc_b[gq * 8 + i], 0.0f);
}

// r0 GEMM partials: grid 256 = kc (Kc=64). Block computes full 64b x 256rh tile
// for its k-chunk via outer product; writes part[kc][b][rh].
__global__ __launch_bounds__(256) void k_r0(const float* __restrict__ yg,
    const float* __restrict__ r0_w, float* __restrict__ part) {
  __shared__ float ygs[64 * 68];   // ygT[k][b], row stride 68
  __shared__ float wts[64 * 260];  // wT[k][rh], row stride 260
  int kc = blockIdx.x, t = threadIdx.x;
  int k0 = kc * 64;
  // stage wT: c = t>>4 selects k-group (store lanes spread 32 banks), rr = t&15
  {
    int c = t >> 4, rr = t & 15;
    for (int rd = 0; rd < 16; rd++) {
      int rh = rd * 16 + rr;
      float4 v = *(const float4*)(r0_w + rh * 16384 + k0 + c * 4);
      wts[(4 * c + 0) * 260 + rh] = v.x;
      wts[(4 * c + 1) * 260 + rh] = v.y;
      wts[(4 * c + 2) * 260 + rh] = v.z;
      wts[(4 * c + 3) * 260 + rh] = v.w;
    }
  }
  // stage ygT
  {
    int b = t >> 2, kq = t & 3;
    const float* src = yg + b * 16384 + k0 + kq * 16;
#pragma unroll
    for (int u = 0; u < 4; u++) {
      float4 v = *(const float4*)(src + u * 4);
      int kk = kq * 16 + u * 4;
      ygs[(kk + 0) * 68 + b] = v.x;
      ygs[(kk + 1) * 68 + b] = v.y;
      ygs[(kk + 2) * 68 + b] = v.z;
      ygs[(kk + 3) * 68 + b] = v.w;
    }
  }
  __syncthreads();
  int lane = t & 63, wv = t >> 6;
  int b8 = lane & 7, r8 = lane >> 3;
  const float* yp = ygs + b8 * 8;
  const float* wp = wts + wv * 64 + r8 * 8;
  float acc[8][8];
#pragma unroll
  for (int i = 0; i < 8; i++)
#pragma unroll
    for (int j = 0; j < 8; j++) acc[i][j] = 0.0f;
#pragma unroll 2
  for (int k = 0; k < 64; k++) {
    float4 ya = *(const float4*)(yp + k * 68);
    float4 yb = *(const float4*)(yp + k * 68 + 4);
    float4 wa = *(const float4*)(wp + k * 260);
    float4 wb = *(const float4*)(wp + k * 260 + 4);
    float yv[8] = {ya.x, ya.y, ya.z, ya.w, yb.x, yb.y, yb.z, yb.w};
    float wr[8] = {wa.x, wa.y, wa.z, wa.w, wb.x, wb.y, wb.z, wb.w};
#pragma unroll
    for (int i = 0; i < 8; i++)
#pragma unroll
      for (int j = 0; j < 8; j++) acc[i][j] += yv[i] * wr[j];
  }
  float* pb = part + kc * 16384 + wv * 64 + r8 * 8;
#pragma unroll
  for (int i = 0; i < 8; i++) {
    float4 s0 = make_float4(acc[i][0], acc[i][1], acc[i][2], acc[i][3]);
    float4 s1 = make_float4(acc[i][4], acc[i][5], acc[i][6], acc[i][7]);
    float* pp = pb + (b8 * 8 + i) * 256;
    *(float4*)pp = s0;
    *(float4*)(pp + 4) = s1;
  }
}

// Reduce partials: grid 256 = (kq 4) x (oq 64). hbuf[o] += sum_{kc in kq} part[kc][o]
__global__ __launch_bounds__(256) void k_r0red(const float* __restrict__ part,
    float* __restrict__ hbuf) {
  int blk = blockIdx.x;
  int oq = blk & 63, kq = blk >> 6;
  int o = oq * 256 + threadIdx.x;
  float s = 0.0f;
  const float* pp = part + kq * 64 * 16384 + o;
#pragma unroll 8
  for (int kc = 0; kc < 64; kc++) s += pp[kc * 16384];
  atomicAdd(&hbuf[o], s);
}

// grid 256 = (bb, pq): wt for 64 p's, partial res over those p's -> res4[pq][b][g]
__global__ __launch_bounds__(256) void k_wt_res(const float* __restrict__ hbuf,
    const float* __restrict__ r3_w, const float* __restrict__ r3_b,
    const float* __restrict__ yg, float* __restrict__ res4) {
  __shared__ float hs[256];
  __shared__ float wts[64];
  __shared__ float red[256];
  int blk = blockIdx.x;
  int bb = blk >> 2, pq = blk & 3;
  int t = threadIdx.x;
  float hv = hbuf[bb * 256 + t];
  hs[t] = hv > 0.0f ? hv : 0.01f * hv;
  __syncthreads();
  int pl = t >> 2, c = t & 3;
  int pp = pq * 64 + pl;
  const float4* wrow = (const float4*)(r3_w + pp * 256 + c * 64);
  const float4* h4 = (const float4*)(hs) + c * 16;
  float a = 0.0f;
#pragma unroll
  for (int j = 0; j < 16; j++) {
    float4 w4 = wrow[j], hh = h4[j];
    a += hh.x * w4.x + hh.y * w4.y + hh.z * w4.z + hh.w * w4.w;
  }
  a += __shfl_xor(a, 1);
  a += __shfl_xor(a, 2);
  if (c == 0) wts[pl] = fmaxf(a + r3_b[pp], 0.0f);
  __syncthreads();
  int g = t & 63, ch = t >> 6;
  float r = 0.0f;
  const float* ygp = yg + bb * 16384 + pq * 4096 + g;
#pragma unroll
  for (int pi = 0; pi < 16; pi++) {
    int pl2 = ch * 16 + pi;
    r += wts[pl2] * ygp[pl2 * 64];
  }
  red[t] = r;
  __syncthreads();
  if (t < 64)
    res4[pq * 4096 + bb * 64 + t] = red[t] + red[t + 64] + red[t + 128] + red[t + 192];
}

// z = elu([sum(res4), x2] @ l1_w^T + l1_b); out = z @ l3_w^T + l3_b
__global__ __launch_bounds__(128) void k_final(const float* __restrict__ res4,
    const float* __restrict__ x2, const float* __restrict__ l1_w,
    const float* __restrict__ l1_b, const float* __restrict__ l3_w,
    const float* __restrict__ l3_b, float* __restrict__ out) {
  __shared__ float zs[128];
  int bb = blockIdx.x, t = threadIdx.x;
  float acc = l1_b[t];
  const float* wrow = l1_w + t * 72;
  const float* rr = res4 + bb * 64;
#pragma unroll 8
  for (int j = 0; j < 64; j++) {
    float rv = rr[j] + rr[4096 + j] + rr[8192 + j] + rr[12288 + j];
    acc += rv * wrow[j];
  }
  const float* xr = x2 + bb * 8;
#pragma unroll
  for (int j = 0; j < 8; j++) acc += xr[j] * wrow[64 + j];
  zs[t] = acc > 0.0f ? acc : expm1f(acc);
  __syncthreads();
  if (t < 9) {
    float o = l3_b[t];
    const float* w3 = l3_w + t * 128;
    for (int j = 0; j < 128; j++) o += zs[j] * w3[j];
    out[bb * 9 + t] = o;
  }
}

extern "C" void kernel_launch(void* const* d_in, const int* in_sizes, int n_in,
                              void* d_out, int out_size, void* d_ws, size_t ws_size,
                              hipStream_t stream) {
  (void)in_sizes; (void)n_in; (void)out_size; (void)ws_size;
  const float* x1     = (const float*)d_in[0];
  const float* x2     = (const float*)d_in[1];
  const float* conv_w = (const float*)d_in[2];
  const float* conv_b = (const float*)d_in[3];
  const float* k1_w   = (const float*)d_in[4];
  const float* k1_b   = (const float*)d_in[5];
  const float* k2_w   = (const float*)d_in[6];
  const float* k3_w   = (const float*)d_in[7];
  const float* k4_w   = (const float*)d_in[8];
  const float* k5_w   = (const float*)d_in[9];
  const float* k5_b   = (const float*)d_in[10];
  const float* gc_w   = (const float*)d_in[11];
  const float* gc_b   = (const float*)d_in[12];
  const float* r0_w   = (const float*)d_in[13];
  const float* r1_w   = (const float*)d_in[14];
  const float* r1_b   = (const float*)d_in[15];
  const float* r2_w   = (const float*)d_in[16];
  const float* r3_w   = (const float*)d_in[17];
  const float* r3_b   = (const float*)d_in[18];
  const float* l1_w   = (const float*)d_in[19];
  const float* l1_b   = (const float*)d_in[20];
  const float* l3_w   = (const float*)d_in[21];
  const float* l3_b   = (const float*)d_in[22];
  const float* ef     = (const float*)d_in[23];
  const float* linc   = (const float*)d_in[24];
  const float* rinc   = (const float*)d_in[25];
  const float* cap    = (const float*)d_in[26];
  const int*   pidx   = (const int*)d_in[27];
  float* out = (float*)d_out;

  float* ws   = (float*)d_ws;
  float* xbuf = ws + X_OFF;
  float* t4   = ws + T4_OFF;
  float* t3   = ws + T3_OFF;
  float* kb   = ws + KB_OFF;
  float* kv   = ws + KW_OFF;
  float* yg   = ws + YG_OFF;
  float* hbuf = ws + HB_OFF;
  float* res4 = ws + RES_OFF;
  float* part = ws + X_OFF;   // aliases x/t4/t3 (dead after k_agg); kv NOT overlapped
  int* ib = (int*)(ws + INT_OFF);
  int* lidx = ib;
  int* ridx = ib + 4096;
  int* part_start = ib + 8192;
  int2* pe2 = (int2*)(ib + 8704);   // 4096 int2 = 8192 ints

  hipLaunchKernelGGL(k_dc, dim3(3584), dim3(256), 0, stream,
                     linc, rinc, lidx, ridx, x1, conv_w, conv_b, xbuf);
  hipLaunchKernelGGL(k_prep, dim3(1857), dim3(256), 0, stream,
                     xbuf, pidx, k3_w, k4_w, x2, k2_w, ef, k1_w, k1_b,
                     r1_w, r1_b, r2_w, cap, lidx, ridx,
                     t4, t3, kb, hbuf, part_start, pe2);
  hipLaunchKernelGGL(k_kern, dim3(4096), dim3(256), 0, stream,
                     kb, t3, t4, k5_w, k5_b, pe2, kv);
  hipLaunchKernelGGL(k_agg, dim3(256), dim3(512), 0, stream,
                     xbuf, kv, pe2, part_start, gc_w, gc_b, yg);
  hipLaunchKernelGGL(k_r0, dim3(256), dim3(256), 0, stream, yg, r0_w, part);
  hipLaunchKernelGGL(k_r0red, dim3(256), dim3(256), 0, stream, part, hbuf);
  hipLaunchKernelGGL(k_wt_res, dim3(256), dim3(256), 0, stream, hbuf, r3_w, r3_b, yg, res4);
  hipLaunchKernelGGL(k_final, dim3(64), dim3(128), 0, stream,
                     res4, x2, l1_w, l1_b, l3_w, l3_b, out);
}

// Round 7
// 237.294 us; speedup vs baseline: 1.0993x; 1.0142x over previous
//
#include <hip/hip_runtime.h>
#include <math.h>

#define B_ 64
#define N_ 512
#define P_ 256
#define E_ 4096
#define F_ 32
#define H_ 64
#define W_ 8
#define G_ 64
#define RH_ 256

// ---- workspace layout (float offsets) ----
#define X_OFF   0
#define T4_OFF  (X_OFF + N_*B_*F_)       // x:  [n][b][f] fp32
#define T3_OFF  (T4_OFF + N_*B_*H_)      // t4 slot: t4h bf16 [n][b][h] (1M fl) + xh bf16 [n][b][f] (512K fl)
#define KB_OFF  (T3_OFF + P_*B_*H_)      // t3: [p][b][h] fp32
#define KW_OFF  (KB_OFF + E_*H_)         // kb: [e][h] fp32
#define YG_OFF  (KW_OFF + E_*B_*W_)      // kv: [pos][b][w] fp32
#define HB_OFF  (YG_OFF + B_*P_*G_)      // yg: [b][p*64+g]
#define RES_OFF (HB_OFF + B_*RH_)        // hbuf: [b][rh]
#define INT_OFF (RES_OFF + 4*B_*G_)      // res4: [pq][b][g]
// int region at INT_OFF: lidx[4096] | ridx[4096] | part_start[512] | pe2[4096 int2]
// r0 partials (4M floats = 16 MB) alias X_OFF..T3 end (x/t4h/xh/t3 dead after k_agg)

__device__ __forceinline__ unsigned short f2bf(float f) {
  unsigned int u = __float_as_uint(f);
  u = u + 0x7fffu + ((u >> 16) & 1u);
  return (unsigned short)(u >> 16);
}

// ---------------------------------------------------------------------------
// Fused: blocks [0,3072) decode linc/rinc -> lidx/ridx; blocks [3072,3584) conv.
__global__ __launch_bounds__(256) void k_dc(
    const float* __restrict__ linc, const float* __restrict__ rinc,
    int* __restrict__ lidx, int* __restrict__ ridx,
    const float* __restrict__ x1, const float* __restrict__ conv_w,
    const float* __restrict__ conv_b, float* __restrict__ x,
    unsigned short* __restrict__ xh) {
  __shared__ float wsm[32 * 132];
  __shared__ float xsm[8192];
  int blk = blockIdx.x, t = threadIdx.x;
  if (blk < 3072) {
    int i4 = blk * 256 + t;
    const int L4 = (P_ * E_) / 4;  // 262144
    if (i4 < L4) {
      float4 v = ((const float4*)linc)[i4];
      int i = i4 * 4;
      int p = i >> 12, e = i & 4095;
      if (v.x != 0.0f) lidx[e]     = p;
      if (v.y != 0.0f) lidx[e + 1] = p;
      if (v.z != 0.0f) lidx[e + 2] = p;
      if (v.w != 0.0f) lidx[e + 3] = p;
    } else {
      int j4 = i4 - L4;
      float4 v = ((const float4*)rinc)[j4];
      int j = j4 * 4;
      int e = j >> 9, n = j & 511;
      if (v.x != 0.0f) ridx[e] = n;
      if (v.y != 0.0f) ridx[e] = n + 1;
      if (v.z != 0.0f) ridx[e] = n + 2;
      if (v.w != 0.0f) ridx[e] = n + 3;
    }
    return;
  }
  // ---- grouped conv (K=16, VALID, 1 out pos) + bias + relu -> x[n][b][f] ----
  int n = blk - 3072;
  for (int i = t; i < 1024; i += 256) {
    int f = i >> 5, j = i & 31;
    ((float4*)wsm)[f * 33 + j] = ((const float4*)(conv_w + n * 4096))[i];
  }
  for (int i = t; i < 2048; i += 256) {
    int b = i >> 5, j = i & 31;
    ((float4*)xsm)[i] = ((const float4*)(x1 + b * 65536 + n * 128))[j];
  }
  __syncthreads();
  int f = t & 31, bq = t >> 5;
  float cb = conv_b[n * 32 + f];
  float acc[8];
#pragma unroll
  for (int bi = 0; bi < 8; bi++) acc[bi] = cb;
  const float4* wf4 = (const float4*)wsm + f * 33;
  const float4* xb4 = (const float4*)xsm + bq * 256;
#pragma unroll 4
  for (int k4 = 0; k4 < 32; k4++) {
    float4 wv = wf4[k4];
#pragma unroll
    for (int bi = 0; bi < 8; bi++) {
      float4 xv = xb4[bi * 32 + k4];
      acc[bi] += wv.x * xv.x + wv.y * xv.y + wv.z * xv.z + wv.w * xv.w;
    }
  }
#pragma unroll
  for (int bi = 0; bi < 8; bi++) {
    int b = bq * 8 + bi;
    float vv = fmaxf(acc[bi], 0.0f);
    x[n * 2048 + b * 32 + f] = vv;
    xh[n * 2048 + b * 32 + f] = f2bf(vv);
  }
}

// blocks [0,512): t4h[n][b][h] = bf16(x[n]@k4_w^T + x2@k2_w^T)
// blocks [512,768): t3[p][b][h] = x[pidx[p]]@k3_w^T  (fp32)
// blocks [768,1792): kb[e][h] = ef[e,:8]@k1_w^T + k1_b
// blocks [1792,1856): hbuf[b][rh] = x2@r1_w^T + r1_b + cap@r2_w^T
// block 1856: counting-sort edges by partition -> part_start, pe2 = (e|p<<16, r)
__global__ __launch_bounds__(256) void k_prep(
    const float* __restrict__ x, const int* __restrict__ pidx,
    const float* __restrict__ k3_w, const float* __restrict__ k4_w,
    const float* __restrict__ x2, const float* __restrict__ k2_w,
    const float* __restrict__ ef, const float* __restrict__ k1_w,
    const float* __restrict__ k1_b,
    const float* __restrict__ r1_w, const float* __restrict__ r1_b,
    const float* __restrict__ r2_w, const float* __restrict__ cap,
    const int* __restrict__ lidx, const int* __restrict__ ridx,
    unsigned short* __restrict__ t4h, float* __restrict__ t3,
    float* __restrict__ kb, float* __restrict__ hbuf,
    int* __restrict__ part_start, int2* __restrict__ pe2) {
  __shared__ float xsh[2048];
  __shared__ float wsh[64 * 36];
  __shared__ float x2s[512];
  __shared__ float k2s[512];
  __shared__ int cnt[256];
  __shared__ int buf[256];
  __shared__ int cur[256];
  int blk = blockIdx.x, t = threadIdx.x;
  if (blk < 768) {
    bool isT4 = blk < 512;
    int n = isT4 ? blk : pidx[blk - 512];
    const float* wmat = isT4 ? k4_w : k3_w;
    float* outp = t3 + (isT4 ? 0 : (blk - 512) * 4096);
    for (int i = t; i < 512; i += 256) {
      ((float4*)xsh)[i] = ((const float4*)(x + n * 2048))[i];
      int h = i >> 3, j = i & 7;
      ((float4*)wsh)[h * 9 + j] = ((const float4*)wmat)[i];
    }
    if (isT4) {
      for (int i = t; i < 128; i += 256) {
        ((float4*)x2s)[i] = ((const float4*)x2)[i];
        ((float4*)k2s)[i] = ((const float4*)k2_w)[i];
      }
    }
    __syncthreads();
    int h = t & 63, bq = t >> 6;
    float wreg[32];
#pragma unroll
    for (int j = 0; j < 8; j++) {
      float4 v = ((float4*)wsh)[h * 9 + j];
      wreg[4 * j] = v.x; wreg[4 * j + 1] = v.y; wreg[4 * j + 2] = v.z; wreg[4 * j + 3] = v.w;
    }
    float w2[8];
    if (isT4) {
      float4 u = ((float4*)k2s)[h * 2], v = ((float4*)k2s)[h * 2 + 1];
      w2[0] = u.x; w2[1] = u.y; w2[2] = u.z; w2[3] = u.w;
      w2[4] = v.x; w2[5] = v.y; w2[6] = v.z; w2[7] = v.w;
    }
    for (int bi = 0; bi < 16; bi++) {
      int b = bq * 16 + bi;
      float acc = 0.0f;
#pragma unroll
      for (int j = 0; j < 8; j++) {
        float4 xv = ((float4*)xsh)[b * 8 + j];
        acc += xv.x * wreg[4 * j] + xv.y * wreg[4 * j + 1] +
               xv.z * wreg[4 * j + 2] + xv.w * wreg[4 * j + 3];
      }
      if (isT4) {
        float4 u = ((float4*)x2s)[b * 2], v = ((float4*)x2s)[b * 2 + 1];
        acc += u.x * w2[0] + u.y * w2[1] + u.z * w2[2] + u.w * w2[3] +
               v.x * w2[4] + v.y * w2[5] + v.z * w2[6] + v.w * w2[7];
        t4h[blk * 4096 + b * 64 + h] = f2bf(acc);
      } else {
        outp[b * 64 + h] = acc;
      }
    }
  } else if (blk < 1792) {
    int o = (blk - 768) * 256 + t;
    int e = o >> 6, h = o & 63;
    float acc = k1_b[h];
    const float* er = ef + e * 9;
    const float* kr = k1_w + h * 8;
#pragma unroll
    for (int d = 0; d < 8; d++) acc += er[d] * kr[d];
    kb[o] = acc;
  } else if (blk < 1856) {
    int o = (blk - 1792) * 256 + t;
    int rh = o & 255;
    float acc = r1_b[rh];
    const float* xr = x2 + (o >> 8) * 8;
    const float* rr = r1_w + rh * 8;
#pragma unroll
    for (int d = 0; d < 8; d++) acc += xr[d] * rr[d];
    const float* r2r = r2_w + rh * 256;
    for (int p4 = 0; p4 < 64; p4++) {
      float4 cv = ((const float4*)cap)[p4];
      float4 rv = ((const float4*)r2r)[p4];
      acc += cv.x * rv.x + cv.y * rv.y + cv.z * rv.z + cv.w * rv.w;
    }
    hbuf[o] = acc;
  } else {
    // ---- counting sort (single block, 256 threads) ----
    cnt[t] = 0;
    __syncthreads();
    for (int e = t; e < E_; e += 256) atomicAdd(&cnt[lidx[e]], 1);
    __syncthreads();
    buf[t] = cnt[t];
    __syncthreads();
    for (int off = 1; off < 256; off <<= 1) {
      int add = (t >= off) ? buf[t - off] : 0;
      __syncthreads();
      buf[t] += add;
      __syncthreads();
    }
    part_start[t + 1] = buf[t];
    if (t == 0) part_start[0] = 0;
    cur[t] = buf[t] - cnt[t];
    __syncthreads();
    for (int e = t; e < E_; e += 256) {
      int p = lidx[e];
      int pos = atomicAdd(&cur[p], 1);
      pe2[pos] = make_int2(e | (p << 16), ridx[e]);
    }
  }
}

// Per-edge kernel MLP: one block per sorted edge position (grid 4096).
// kv[pos][b][w] = relu(sum_h leaky(kb[e,h]+t3[p,b,h]+t4h[r,b,h]) * k5[w,h] + b5[w])
// t4 gather is bf16 (half the bytes of round 6). XCD-bijective pos swizzle keeps
// same-partition blocks (shared t3 row) on one XCD's L2.
__global__ __launch_bounds__(256) void k_kern(
    const float* __restrict__ kb, const float* __restrict__ t3,
    const unsigned short* __restrict__ t4h, const float* __restrict__ k5_w,
    const float* __restrict__ k5_b, const int2* __restrict__ pe2,
    float* __restrict__ kv) {
  __shared__ float k5t[4 * 520];   // s-replicated [h][w]
  int bid = blockIdx.x;
  int pos = (bid & 7) * 512 + (bid >> 3);   // 4096 % 8 == 0 -> bijective
  int t = threadIdx.x;
  for (int i = t; i < 512; i += 256) {
    int h = i >> 3, w = i & 7;
    float v = k5_w[w * 64 + h];
#pragma unroll
    for (int qq = 0; qq < 4; qq++) k5t[qq * 520 + i] = v;
  }
  int2 c = pe2[pos];
  int e = c.x & 0xffff, p = c.x >> 16, r = c.y;
  int s = t & 3, b = t >> 2;
  __syncthreads();
  const float* kq = k5t + s * 520 + s * 128;  // rows h = s*16..s*16+15
  const float4* kb4 = (const float4*)(kb + e * 64 + s * 16);
  const float4* t34 = (const float4*)(t3 + p * 4096 + b * 64 + s * 16);
  const int4* t4p = (const int4*)(t4h + r * 4096 + b * 64 + s * 16);
  int4 ta = t4p[0], tb = t4p[1];   // 16 bf16 values
  float t4v[16];
  {
    unsigned int uu;
    uu = (unsigned int)ta.x; t4v[0]  = __uint_as_float(uu << 16); t4v[1]  = __uint_as_float(uu & 0xffff0000u);
    uu = (unsigned int)ta.y; t4v[2]  = __uint_as_float(uu << 16); t4v[3]  = __uint_as_float(uu & 0xffff0000u);
    uu = (unsigned int)ta.z; t4v[4]  = __uint_as_float(uu << 16); t4v[5]  = __uint_as_float(uu & 0xffff0000u);
    uu = (unsigned int)ta.w; t4v[6]  = __uint_as_float(uu << 16); t4v[7]  = __uint_as_float(uu & 0xffff0000u);
    uu = (unsigned int)tb.x; t4v[8]  = __uint_as_float(uu << 16); t4v[9]  = __uint_as_float(uu & 0xffff0000u);
    uu = (unsigned int)tb.y; t4v[10] = __uint_as_float(uu << 16); t4v[11] = __uint_as_float(uu & 0xffff0000u);
    uu = (unsigned int)tb.z; t4v[12] = __uint_as_float(uu << 16); t4v[13] = __uint_as_float(uu & 0xffff0000u);
    uu = (unsigned int)tb.w; t4v[14] = __uint_as_float(uu << 16); t4v[15] = __uint_as_float(uu & 0xffff0000u);
  }
  float lk[16];
#pragma unroll
  for (int j4 = 0; j4 < 4; j4++) {
    float4 a = kb4[j4], cc = t34[j4];
    float v;
    v = a.x + cc.x + t4v[j4 * 4 + 0]; lk[j4 * 4 + 0] = v > 0.0f ? v : 0.02f * v;
    v = a.y + cc.y + t4v[j4 * 4 + 1]; lk[j4 * 4 + 1] = v > 0.0f ? v : 0.02f * v;
    v = a.z + cc.z + t4v[j4 * 4 + 2]; lk[j4 * 4 + 2] = v > 0.0f ? v : 0.02f * v;
    v = a.w + cc.w + t4v[j4 * 4 + 3]; lk[j4 * 4 + 3] = v > 0.0f ? v : 0.02f * v;
  }
  float pw[8] = {0, 0, 0, 0, 0, 0, 0, 0};
#pragma unroll
  for (int j = 0; j < 16; j++) {
    float4 u = *(const float4*)(kq + j * 8);
    float4 v = *(const float4*)(kq + j * 8 + 4);
    float l = lk[j];
    pw[0] += l * u.x; pw[1] += l * u.y; pw[2] += l * u.z; pw[3] += l * u.w;
    pw[4] += l * v.x; pw[5] += l * v.y; pw[6] += l * v.z; pw[7] += l * v.w;
  }
#pragma unroll
  for (int w = 0; w < 8; w++) {  // reduce over the 4 s-lanes
    pw[w] += __shfl_xor(pw[w], 1);
    pw[w] += __shfl_xor(pw[w], 2);
  }
  float2 o;
  o.x = fmaxf(pw[2 * s] + k5_b[2 * s], 0.0f);
  o.y = fmaxf(pw[2 * s + 1] + k5_b[2 * s + 1], 0.0f);
  *(float2*)(kv + pos * 512 + b * 8 + 2 * s) = o;
}

// Aggregation + gc GEMM, one block (512 thr) per partition, 2 edge-slots.
// Main loop per edge: kv read (contiguous) + bf16 x gather + 64 FMA.
// gc_w staged once into LDS. Slots merge through fp32 accS in two w-half phases.
__global__ __launch_bounds__(512, 2) void k_agg(
    const unsigned short* __restrict__ xh, const float* __restrict__ kv,
    const int2* __restrict__ pe2, const int* __restrict__ part_start,
    const float* __restrict__ gc_w, const float* __restrict__ gc_b,
    float* __restrict__ yg) {
  __shared__ float accS[64 * 128]; // fp32 [b][w-half k], XOR-swizzled (32 KB)
  __shared__ float gcS[64 * 256];  // gc_w staged (64 KB)
  int p = blockIdx.x, t = threadIdx.x;
  int slot = t >> 8;
  int ts = t & 255;
  int s = ts & 3, b = ts >> 2;
  for (int i4 = t; i4 < 4096; i4 += 512)
    ((float4*)gcS)[i4] = ((const float4*)gc_w)[i4];
  float acc[64];   // acc[w*8 + j], f = s*8 + j
#pragma unroll
  for (int j = 0; j < 64; j++) acc[j] = 0.0f;
  int s0 = part_start[p], s1 = part_start[p + 1];
  int idx = s0 + slot;
  int r = (idx < s1) ? pe2[idx].y : 0;
  for (; idx < s1; idx += 2) {
    int rn = (idx + 2 < s1) ? pe2[idx + 2].y : 0;
    const float4* kvp = (const float4*)(kv + idx * 512 + b * 8);
    float4 ka = kvp[0], kc = kvp[1];
    int4 xw = *(const int4*)(xh + r * 2048 + b * 32 + s * 8);
    float kw[8] = {ka.x, ka.y, ka.z, ka.w, kc.x, kc.y, kc.z, kc.w};
    float xa[8];
    {
      unsigned int uu;
      uu = (unsigned int)xw.x; xa[0] = __uint_as_float(uu << 16); xa[1] = __uint_as_float(uu & 0xffff0000u);
      uu = (unsigned int)xw.y; xa[2] = __uint_as_float(uu << 16); xa[3] = __uint_as_float(uu & 0xffff0000u);
      uu = (unsigned int)xw.z; xa[4] = __uint_as_float(uu << 16); xa[5] = __uint_as_float(uu & 0xffff0000u);
      uu = (unsigned int)xw.w; xa[6] = __uint_as_float(uu << 16); xa[7] = __uint_as_float(uu & 0xffff0000u);
    }
#pragma unroll
    for (int w = 0; w < 8; w++)
#pragma unroll
      for (int j = 0; j < 8; j++) acc[w * 8 + j] += kw[w] * xa[j];
    r = rn;
  }
  // ---- slot merge + gc GEMM in two w-half phases (fp32 exact) ----
  int gq = t >> 6, be = t & 63;
  float ac[8];
#pragma unroll
  for (int i = 0; i < 8; i++) ac[i] = 0.0f;
#pragma unroll
  for (int ph = 0; ph < 2; ph++) {
    if (ph) __syncthreads();  // protect accS while phase-0 reads finish
    if (slot == 0) {
#pragma unroll
      for (int w2 = 0; w2 < 4; w2++)
#pragma unroll
        for (int j4 = 0; j4 < 2; j4++) {
          int khalf4 = w2 * 8 + s * 2 + j4;
          int phys4 = (khalf4 & 24) | ((khalf4 ^ b) & 7);
          int j = (ph * 4 + w2) * 8 + j4 * 4;
          *(float4*)(accS + b * 128 + phys4 * 4) =
              make_float4(acc[j], acc[j + 1], acc[j + 2], acc[j + 3]);
        }
    }
    __syncthreads();
    if (slot == 1) {
#pragma unroll
      for (int w2 = 0; w2 < 4; w2++)
#pragma unroll
        for (int j4 = 0; j4 < 2; j4++) {
          int khalf4 = w2 * 8 + s * 2 + j4;
          int phys4 = (khalf4 & 24) | ((khalf4 ^ b) & 7);
          int j = (ph * 4 + w2) * 8 + j4 * 4;
          float4* ptr = (float4*)(accS + b * 128 + phys4 * 4);
          float4 o = *ptr;
          o.x += acc[j]; o.y += acc[j + 1]; o.z += acc[j + 2]; o.w += acc[j + 3];
          *ptr = o;
        }
    }
    __syncthreads();
    // epilogue partial over this w-half: wave gq -> g [gq*8,gq*8+8), lane = b row
    for (int k4h = 0; k4h < 32; k4h++) {
      int phys4 = (k4h & 24) | ((k4h ^ be) & 7);
      float4 av = *(const float4*)(accS + be * 128 + phys4 * 4);
      int w2 = k4h >> 3;
      int k4g = (ph * 4 + w2) * 8 + (k4h & 7);  // global float4 col
#pragma unroll
      for (int i = 0; i < 8; i++) {
        float4 wv = *(const float4*)(gcS + (gq * 8 + i) * 256 + k4g * 4);
        ac[i] += av.x * wv.x + av.y * wv.y + av.z * wv.z + av.w * wv.w;
      }
    }
  }
  float* yp = yg + be * 16384 + p * 64 + gq * 8;
#pragma unroll
  for (int i = 0; i < 8; i++)
    yp[i] = fmaxf(ac[i] + gc_b[gq * 8 + i], 0.0f);
}

// r0 GEMM partials: grid 256 = kc (Kc=64). Block computes full 64b x 256rh tile
// for its k-chunk via outer product; writes part[kc][b][rh].
__global__ __launch_bounds__(256) void k_r0(const float* __restrict__ yg,
    const float* __restrict__ r0_w, float* __restrict__ part) {
  __shared__ float ygs[64 * 68];   // ygT[k][b], row stride 68
  __shared__ float wts[64 * 260];  // wT[k][rh], row stride 260
  int kc = blockIdx.x, t = threadIdx.x;
  int k0 = kc * 64;
  // stage wT: c = t>>4 selects k-group (store lanes spread 32 banks), rr = t&15
  {
    int c = t >> 4, rr = t & 15;
    for (int rd = 0; rd < 16; rd++) {
      int rh = rd * 16 + rr;
      float4 v = *(const float4*)(r0_w + rh * 16384 + k0 + c * 4);
      wts[(4 * c + 0) * 260 + rh] = v.x;
      wts[(4 * c + 1) * 260 + rh] = v.y;
      wts[(4 * c + 2) * 260 + rh] = v.z;
      wts[(4 * c + 3) * 260 + rh] = v.w;
    }
  }
  // stage ygT
  {
    int b = t >> 2, kq = t & 3;
    const float* src = yg + b * 16384 + k0 + kq * 16;
#pragma unroll
    for (int u = 0; u < 4; u++) {
      float4 v = *(const float4*)(src + u * 4);
      int kk = kq * 16 + u * 4;
      ygs[(kk + 0) * 68 + b] = v.x;
      ygs[(kk + 1) * 68 + b] = v.y;
      ygs[(kk + 2) * 68 + b] = v.z;
      ygs[(kk + 3) * 68 + b] = v.w;
    }
  }
  __syncthreads();
  int lane = t & 63, wv = t >> 6;
  int b8 = lane & 7, r8 = lane >> 3;
  const float* yp = ygs + b8 * 8;
  const float* wp = wts + wv * 64 + r8 * 8;
  float acc[8][8];
#pragma unroll
  for (int i = 0; i < 8; i++)
#pragma unroll
    for (int j = 0; j < 8; j++) acc[i][j] = 0.0f;
#pragma unroll 2
  for (int k = 0; k < 64; k++) {
    float4 ya = *(const float4*)(yp + k * 68);
    float4 yb = *(const float4*)(yp + k * 68 + 4);
    float4 wa = *(const float4*)(wp + k * 260);
    float4 wb = *(const float4*)(wp + k * 260 + 4);
    float yv[8] = {ya.x, ya.y, ya.z, ya.w, yb.x, yb.y, yb.z, yb.w};
    float wr[8] = {wa.x, wa.y, wa.z, wa.w, wb.x, wb.y, wb.z, wb.w};
#pragma unroll
    for (int i = 0; i < 8; i++)
#pragma unroll
      for (int j = 0; j < 8; j++) acc[i][j] += yv[i] * wr[j];
  }
  float* pb = part + kc * 16384 + wv * 64 + r8 * 8;
#pragma unroll
  for (int i = 0; i < 8; i++) {
    float4 s0 = make_float4(acc[i][0], acc[i][1], acc[i][2], acc[i][3]);
    float4 s1 = make_float4(acc[i][4], acc[i][5], acc[i][6], acc[i][7]);
    float* pp = pb + (b8 * 8 + i) * 256;
    *(float4*)pp = s0;
    *(float4*)(pp + 4) = s1;
  }
}

// Reduce partials: grid 256 = (kq 4) x (oq 64). hbuf[o] += sum_{kc in kq} part[kc][o]
__global__ __launch_bounds__(256) void k_r0red(const float* __restrict__ part,
    float* __restrict__ hbuf) {
  int blk = blockIdx.x;
  int oq = blk & 63, kq = blk >> 6;
  int o = oq * 256 + threadIdx.x;
  float s = 0.0f;
  const float* pp = part + kq * 64 * 16384 + o;
#pragma unroll 8
  for (int kc = 0; kc < 64; kc++) s += pp[kc * 16384];
  atomicAdd(&hbuf[o], s);
}

// grid 256 = (bb, pq): wt for 64 p's, partial res over those p's -> res4[pq][b][g]
__global__ __launch_bounds__(256) void k_wt_res(const float* __restrict__ hbuf,
    const float* __restrict__ r3_w, const float* __restrict__ r3_b,
    const float* __restrict__ yg, float* __restrict__ res4) {
  __shared__ float hs[256];
  __shared__ float wts[64];
  __shared__ float red[256];
  int blk = blockIdx.x;
  int bb = blk >> 2, pq = blk & 3;
  int t = threadIdx.x;
  float hv = hbuf[bb * 256 + t];
  hs[t] = hv > 0.0f ? hv : 0.01f * hv;
  __syncthreads();
  int pl = t >> 2, c = t & 3;
  int pp = pq * 64 + pl;
  const float4* wrow = (const float4*)(r3_w + pp * 256 + c * 64);
  const float4* h4 = (const float4*)(hs) + c * 16;
  float a = 0.0f;
#pragma unroll
  for (int j = 0; j < 16; j++) {
    float4 w4 = wrow[j], hh = h4[j];
    a += hh.x * w4.x + hh.y * w4.y + hh.z * w4.z + hh.w * w4.w;
  }
  a += __shfl_xor(a, 1);
  a += __shfl_xor(a, 2);
  if (c == 0) wts[pl] = fmaxf(a + r3_b[pp], 0.0f);
  __syncthreads();
  int g = t & 63, ch = t >> 6;
  float r = 0.0f;
  const float* ygp = yg + bb * 16384 + pq * 4096 + g;
#pragma unroll
  for (int pi = 0; pi < 16; pi++) {
    int pl2 = ch * 16 + pi;
    r += wts[pl2] * ygp[pl2 * 64];
  }
  red[t] = r;
  __syncthreads();
  if (t < 64)
    res4[pq * 4096 + bb * 64 + t] = red[t] + red[t + 64] + red[t + 128] + red[t + 192];
}

// z = elu([sum(res4), x2] @ l1_w^T + l1_b); out = z @ l3_w^T + l3_b
__global__ __launch_bounds__(128) void k_final(const float* __restrict__ res4,
    const float* __restrict__ x2, const float* __restrict__ l1_w,
    const float* __restrict__ l1_b, const float* __restrict__ l3_w,
    const float* __restrict__ l3_b, float* __restrict__ out) {
  __shared__ float zs[128];
  int bb = blockIdx.x, t = threadIdx.x;
  float acc = l1_b[t];
  const float* wrow = l1_w + t * 72;
  const float* rr = res4 + bb * 64;
#pragma unroll 8
  for (int j = 0; j < 64; j++) {
    float rv = rr[j] + rr[4096 + j] + rr[8192 + j] + rr[12288 + j];
    acc += rv * wrow[j];
  }
  const float* xr = x2 + bb * 8;
#pragma unroll
  for (int j = 0; j < 8; j++) acc += xr[j] * wrow[64 + j];
  zs[t] = acc > 0.0f ? acc : expm1f(acc);
  __syncthreads();
  if (t < 9) {
    float o = l3_b[t];
    const float* w3 = l3_w + t * 128;
    for (int j = 0; j < 128; j++) o += zs[j] * w3[j];
    out[bb * 9 + t] = o;
  }
}

extern "C" void kernel_launch(void* const* d_in, const int* in_sizes, int n_in,
                              void* d_out, int out_size, void* d_ws, size_t ws_size,
                              hipStream_t stream) {
  (void)in_sizes; (void)n_in; (void)out_size; (void)ws_size;
  const float* x1     = (const float*)d_in[0];
  const float* x2     = (const float*)d_in[1];
  const float* conv_w = (const float*)d_in[2];
  const float* conv_b = (const float*)d_in[3];
  const float* k1_w   = (const float*)d_in[4];
  const float* k1_b   = (const float*)d_in[5];
  const float* k2_w   = (const float*)d_in[6];
  const float* k3_w   = (const float*)d_in[7];
  const float* k4_w   = (const float*)d_in[8];
  const float* k5_w   = (const float*)d_in[9];
  const float* k5_b   = (const float*)d_in[10];
  const float* gc_w   = (const float*)d_in[11];
  const float* gc_b   = (const float*)d_in[12];
  const float* r0_w   = (const float*)d_in[13];
  const float* r1_w   = (const float*)d_in[14];
  const float* r1_b   = (const float*)d_in[15];
  const float* r2_w   = (const float*)d_in[16];
  const float* r3_w   = (const float*)d_in[17];
  const float* r3_b   = (const float*)d_in[18];
  const float* l1_w   = (const float*)d_in[19];
  const float* l1_b   = (const float*)d_in[20];
  const float* l3_w   = (const float*)d_in[21];
  const float* l3_b   = (const float*)d_in[22];
  const float* ef     = (const float*)d_in[23];
  const float* linc   = (const float*)d_in[24];
  const float* rinc   = (const float*)d_in[25];
  const float* cap    = (const float*)d_in[26];
  const int*   pidx   = (const int*)d_in[27];
  float* out = (float*)d_out;

  float* ws   = (float*)d_ws;
  float* xbuf = ws + X_OFF;
  unsigned short* t4h = (unsigned short*)(ws + T4_OFF);              // 2M bf16 = 1M floats
  unsigned short* xh  = (unsigned short*)(ws + T4_OFF + N_*B_*H_/2); // 1M bf16 = 512K floats
  float* t3   = ws + T3_OFF;
  float* kb   = ws + KB_OFF;
  float* kv   = ws + KW_OFF;
  float* yg   = ws + YG_OFF;
  float* hbuf = ws + HB_OFF;
  float* res4 = ws + RES_OFF;
  float* part = ws + X_OFF;   // aliases x/t4h/xh/t3 (dead after k_agg); kv NOT overlapped
  int* ib = (int*)(ws + INT_OFF);
  int* lidx = ib;
  int* ridx = ib + 4096;
  int* part_start = ib + 8192;
  int2* pe2 = (int2*)(ib + 8704);   // 4096 int2 = 8192 ints

  hipLaunchKernelGGL(k_dc, dim3(3584), dim3(256), 0, stream,
                     linc, rinc, lidx, ridx, x1, conv_w, conv_b, xbuf, xh);
  hipLaunchKernelGGL(k_prep, dim3(1857), dim3(256), 0, stream,
                     xbuf, pidx, k3_w, k4_w, x2, k2_w, ef, k1_w, k1_b,
                     r1_w, r1_b, r2_w, cap, lidx, ridx,
                     t4h, t3, kb, hbuf, part_start, pe2);
  hipLaunchKernelGGL(k_kern, dim3(4096), dim3(256), 0, stream,
                     kb, t3, t4h, k5_w, k5_b, pe2, kv);
  hipLaunchKernelGGL(k_agg, dim3(256), dim3(512), 0, stream,
                     xh, kv, pe2, part_start, gc_w, gc_b, yg);
  hipLaunchKernelGGL(k_r0, dim3(256), dim3(256), 0, stream, yg, r0_w, part);
  hipLaunchKernelGGL(k_r0red, dim3(256), dim3(256), 0, stream, part, hbuf);
  hipLaunchKernelGGL(k_wt_res, dim3(256), dim3(256), 0, stream, hbuf, r3_w, r3_b, yg, res4);
  hipLaunchKernelGGL(k_final, dim3(64), dim3(128), 0, stream,
                     res4, x2, l1_w, l1_b, l3_w, l3_b, out);
}

// Round 8
// 229.209 us; speedup vs baseline: 1.1381x; 1.0353x over previous
//
#include <hip/hip_runtime.h>
#include <math.h>

#define B_ 64
#define N_ 512
#define P_ 256
#define E_ 4096
#define F_ 32
#define H_ 64
#define W_ 8
#define G_ 64
#define RH_ 256

// ---- workspace layout (float offsets) ----
#define X_OFF   0
#define T4_OFF  (X_OFF + N_*B_*F_)       // x:  [n][b][f] fp32
#define T3_OFF  (T4_OFF + N_*B_*H_)      // t4 slot: t4h bf16 [n][b][h] + xh bf16 [n][b][f]
#define KB_OFF  (T3_OFF + P_*B_*H_)      // t3: [p][b][h] fp32
#define KW_OFF  (KB_OFF + E_*H_)         // kb: [e][h] fp32
#define YG_OFF  (KW_OFF + E_*B_*W_)      // kv: [pos][b][w] fp32
#define HB_OFF  (YG_OFF + B_*P_*G_)      // yg: [b][p*64+g]
#define RES_OFF (HB_OFF + B_*RH_)        // hbuf: [b][rh]
#define INT_OFF (RES_OFF + 4*B_*G_)      // res4: [pq][b][g]
// int region at INT_OFF: lidx[4096] | ridx[4096] | part_start[512] | pe2[4096 int2]
// then capv[256] floats at INT_OFF + 16896.
// r0 partials now only 1M floats (4 MB): alias X_OFF (x fp32, dead after k_prep).

__device__ __forceinline__ unsigned short f2bf(float f) {
  unsigned int u = __float_as_uint(f);
  u = u + 0x7fffu + ((u >> 16) & 1u);
  return (unsigned short)(u >> 16);
}

// ---------------------------------------------------------------------------
// blocks [0,3072): decode linc/rinc -> lidx/ridx
// blocks [3072,3584): grouped conv -> x (fp32) + xh (bf16)
// block 3584: capv[rh] = cap @ r2_w[rh]  (b-independent hbuf term, computed once)
__global__ __launch_bounds__(256) void k_dc(
    const float* __restrict__ linc, const float* __restrict__ rinc,
    int* __restrict__ lidx, int* __restrict__ ridx,
    const float* __restrict__ x1, const float* __restrict__ conv_w,
    const float* __restrict__ conv_b, float* __restrict__ x,
    unsigned short* __restrict__ xh,
    const float* __restrict__ cap, const float* __restrict__ r2_w,
    float* __restrict__ capv) {
  __shared__ float wsm[32 * 132];
  __shared__ float xsm[8192];
  int blk = blockIdx.x, t = threadIdx.x;
  if (blk < 3072) {
    int i4 = blk * 256 + t;
    const int L4 = (P_ * E_) / 4;  // 262144
    if (i4 < L4) {
      float4 v = ((const float4*)linc)[i4];
      int i = i4 * 4;
      int p = i >> 12, e = i & 4095;
      if (v.x != 0.0f) lidx[e]     = p;
      if (v.y != 0.0f) lidx[e + 1] = p;
      if (v.z != 0.0f) lidx[e + 2] = p;
      if (v.w != 0.0f) lidx[e + 3] = p;
    } else {
      int j4 = i4 - L4;
      float4 v = ((const float4*)rinc)[j4];
      int j = j4 * 4;
      int e = j >> 9, n = j & 511;
      if (v.x != 0.0f) ridx[e] = n;
      if (v.y != 0.0f) ridx[e] = n + 1;
      if (v.z != 0.0f) ridx[e] = n + 2;
      if (v.w != 0.0f) ridx[e] = n + 3;
    }
    return;
  }
  if (blk == 3584) {
    // capv[rh] = sum_p cap[p] * r2_w[rh][p]
    float acc = 0.0f;
    const float* rr = r2_w + t * 256;
    for (int p4 = 0; p4 < 64; p4++) {
      float4 cv = ((const float4*)cap)[p4];
      float4 rv = ((const float4*)rr)[p4];
      acc += cv.x * rv.x + cv.y * rv.y + cv.z * rv.z + cv.w * rv.w;
    }
    capv[t] = acc;
    return;
  }
  // ---- grouped conv (K=16, VALID, 1 out pos) + bias + relu -> x[n][b][f] ----
  int n = blk - 3072;
  for (int i = t; i < 1024; i += 256) {
    int f = i >> 5, j = i & 31;
    ((float4*)wsm)[f * 33 + j] = ((const float4*)(conv_w + n * 4096))[i];
  }
  for (int i = t; i < 2048; i += 256) {
    int b = i >> 5, j = i & 31;
    ((float4*)xsm)[i] = ((const float4*)(x1 + b * 65536 + n * 128))[j];
  }
  __syncthreads();
  int f = t & 31, bq = t >> 5;
  float cb = conv_b[n * 32 + f];
  float acc[8];
#pragma unroll
  for (int bi = 0; bi < 8; bi++) acc[bi] = cb;
  const float4* wf4 = (const float4*)wsm + f * 33;
  const float4* xb4 = (const float4*)xsm + bq * 256;
#pragma unroll 4
  for (int k4 = 0; k4 < 32; k4++) {
    float4 wv = wf4[k4];
#pragma unroll
    for (int bi = 0; bi < 8; bi++) {
      float4 xv = xb4[bi * 32 + k4];
      acc[bi] += wv.x * xv.x + wv.y * xv.y + wv.z * xv.z + wv.w * xv.w;
    }
  }
#pragma unroll
  for (int bi = 0; bi < 8; bi++) {
    int b = bq * 8 + bi;
    float vv = fmaxf(acc[bi], 0.0f);
    x[n * 2048 + b * 32 + f] = vv;
    xh[n * 2048 + b * 32 + f] = f2bf(vv);
  }
}

// blocks [0,512): t4h[n][b][h] = bf16(x[n]@k4_w^T + x2@k2_w^T)
// blocks [512,768): t3[p][b][h] = x[pidx[p]]@k3_w^T  (fp32)
// blocks [768,1792): kb[e][h] = ef[e,:8]@k1_w^T + k1_b
// blocks [1792,1856): hbuf[b][rh] = x2@r1_w^T + r1_b + capv[rh]
// block 1856: counting-sort edges by partition -> part_start, pe2 = (e|p<<16, r)
__global__ __launch_bounds__(256) void k_prep(
    const float* __restrict__ x, const int* __restrict__ pidx,
    const float* __restrict__ k3_w, const float* __restrict__ k4_w,
    const float* __restrict__ x2, const float* __restrict__ k2_w,
    const float* __restrict__ ef, const float* __restrict__ k1_w,
    const float* __restrict__ k1_b,
    const float* __restrict__ r1_w, const float* __restrict__ r1_b,
    const float* __restrict__ capv,
    const int* __restrict__ lidx, const int* __restrict__ ridx,
    unsigned short* __restrict__ t4h, float* __restrict__ t3,
    float* __restrict__ kb, float* __restrict__ hbuf,
    int* __restrict__ part_start, int2* __restrict__ pe2) {
  __shared__ float xsh[2048];
  __shared__ float wsh[64 * 36];
  __shared__ float x2s[512];
  __shared__ float k2s[512];
  __shared__ int cnt[256];
  __shared__ int buf[256];
  __shared__ int cur[256];
  int blk = blockIdx.x, t = threadIdx.x;
  if (blk < 768) {
    bool isT4 = blk < 512;
    int n = isT4 ? blk : pidx[blk - 512];
    const float* wmat = isT4 ? k4_w : k3_w;
    float* outp = t3 + (isT4 ? 0 : (blk - 512) * 4096);
    for (int i = t; i < 512; i += 256) {
      ((float4*)xsh)[i] = ((const float4*)(x + n * 2048))[i];
      int h = i >> 3, j = i & 7;
      ((float4*)wsh)[h * 9 + j] = ((const float4*)wmat)[i];
    }
    if (isT4) {
      for (int i = t; i < 128; i += 256) {
        ((float4*)x2s)[i] = ((const float4*)x2)[i];
        ((float4*)k2s)[i] = ((const float4*)k2_w)[i];
      }
    }
    __syncthreads();
    int h = t & 63, bq = t >> 6;
    float wreg[32];
#pragma unroll
    for (int j = 0; j < 8; j++) {
      float4 v = ((float4*)wsh)[h * 9 + j];
      wreg[4 * j] = v.x; wreg[4 * j + 1] = v.y; wreg[4 * j + 2] = v.z; wreg[4 * j + 3] = v.w;
    }
    float w2[8];
    if (isT4) {
      float4 u = ((float4*)k2s)[h * 2], v = ((float4*)k2s)[h * 2 + 1];
      w2[0] = u.x; w2[1] = u.y; w2[2] = u.z; w2[3] = u.w;
      w2[4] = v.x; w2[5] = v.y; w2[6] = v.z; w2[7] = v.w;
    }
    for (int bi = 0; bi < 16; bi++) {
      int b = bq * 16 + bi;
      float acc = 0.0f;
#pragma unroll
      for (int j = 0; j < 8; j++) {
        float4 xv = ((float4*)xsh)[b * 8 + j];
        acc += xv.x * wreg[4 * j] + xv.y * wreg[4 * j + 1] +
               xv.z * wreg[4 * j + 2] + xv.w * wreg[4 * j + 3];
      }
      if (isT4) {
        float4 u = ((float4*)x2s)[b * 2], v = ((float4*)x2s)[b * 2 + 1];
        acc += u.x * w2[0] + u.y * w2[1] + u.z * w2[2] + u.w * w2[3] +
               v.x * w2[4] + v.y * w2[5] + v.z * w2[6] + v.w * w2[7];
        t4h[blk * 4096 + b * 64 + h] = f2bf(acc);
      } else {
        outp[b * 64 + h] = acc;
      }
    }
  } else if (blk < 1792) {
    int o = (blk - 768) * 256 + t;
    int e = o >> 6, h = o & 63;
    float acc = k1_b[h];
    const float* er = ef + e * 9;
    const float* kr = k1_w + h * 8;
#pragma unroll
    for (int d = 0; d < 8; d++) acc += er[d] * kr[d];
    kb[o] = acc;
  } else if (blk < 1856) {
    int o = (blk - 1792) * 256 + t;
    int rh = o & 255;
    float acc = r1_b[rh] + capv[rh];
    const float* xr = x2 + (o >> 8) * 8;
    const float* rr = r1_w + rh * 8;
#pragma unroll
    for (int d = 0; d < 8; d++) acc += xr[d] * rr[d];
    hbuf[o] = acc;
  } else {
    // ---- counting sort (single block, 256 threads) ----
    cnt[t] = 0;
    __syncthreads();
    for (int e = t; e < E_; e += 256) atomicAdd(&cnt[lidx[e]], 1);
    __syncthreads();
    buf[t] = cnt[t];
    __syncthreads();
    for (int off = 1; off < 256; off <<= 1) {
      int add = (t >= off) ? buf[t - off] : 0;
      __syncthreads();
      buf[t] += add;
      __syncthreads();
    }
    part_start[t + 1] = buf[t];
    if (t == 0) part_start[0] = 0;
    cur[t] = buf[t] - cnt[t];
    __syncthreads();
    for (int e = t; e < E_; e += 256) {
      int p = lidx[e];
      int pos = atomicAdd(&cur[p], 1);
      pe2[pos] = make_int2(e | (p << 16), ridx[e]);
    }
  }
}

// Per-edge kernel MLP: one block per sorted edge position (grid 4096).
// kv[pos][b][w] = relu(sum_h leaky(kb[e,h]+t3[p,b,h]+t4h[r,b,h]) * k5[w,h] + b5[w])
__global__ __launch_bounds__(256) void k_kern(
    const float* __restrict__ kb, const float* __restrict__ t3,
    const unsigned short* __restrict__ t4h, const float* __restrict__ k5_w,
    const float* __restrict__ k5_b, const int2* __restrict__ pe2,
    float* __restrict__ kv) {
  __shared__ float k5t[4 * 520];   // s-replicated [h][w]
  int bid = blockIdx.x;
  int pos = (bid & 7) * 512 + (bid >> 3);   // 4096 % 8 == 0 -> bijective
  int t = threadIdx.x;
  for (int i = t; i < 512; i += 256) {
    int h = i >> 3, w = i & 7;
    float v = k5_w[w * 64 + h];
#pragma unroll
    for (int qq = 0; qq < 4; qq++) k5t[qq * 520 + i] = v;
  }
  int2 c = pe2[pos];
  int e = c.x & 0xffff, p = c.x >> 16, r = c.y;
  int s = t & 3, b = t >> 2;
  __syncthreads();
  const float* kq = k5t + s * 520 + s * 128;  // rows h = s*16..s*16+15
  const float4* kb4 = (const float4*)(kb + e * 64 + s * 16);
  const float4* t34 = (const float4*)(t3 + p * 4096 + b * 64 + s * 16);
  const int4* t4p = (const int4*)(t4h + r * 4096 + b * 64 + s * 16);
  int4 ta = t4p[0], tb = t4p[1];   // 16 bf16 values
  float t4v[16];
  {
    unsigned int uu;
    uu = (unsigned int)ta.x; t4v[0]  = __uint_as_float(uu << 16); t4v[1]  = __uint_as_float(uu & 0xffff0000u);
    uu = (unsigned int)ta.y; t4v[2]  = __uint_as_float(uu << 16); t4v[3]  = __uint_as_float(uu & 0xffff0000u);
    uu = (unsigned int)ta.z; t4v[4]  = __uint_as_float(uu << 16); t4v[5]  = __uint_as_float(uu & 0xffff0000u);
    uu = (unsigned int)ta.w; t4v[6]  = __uint_as_float(uu << 16); t4v[7]  = __uint_as_float(uu & 0xffff0000u);
    uu = (unsigned int)tb.x; t4v[8]  = __uint_as_float(uu << 16); t4v[9]  = __uint_as_float(uu & 0xffff0000u);
    uu = (unsigned int)tb.y; t4v[10] = __uint_as_float(uu << 16); t4v[11] = __uint_as_float(uu & 0xffff0000u);
    uu = (unsigned int)tb.z; t4v[12] = __uint_as_float(uu << 16); t4v[13] = __uint_as_float(uu & 0xffff0000u);
    uu = (unsigned int)tb.w; t4v[14] = __uint_as_float(uu << 16); t4v[15] = __uint_as_float(uu & 0xffff0000u);
  }
  float lk[16];
#pragma unroll
  for (int j4 = 0; j4 < 4; j4++) {
    float4 a = kb4[j4], cc = t34[j4];
    float v;
    v = a.x + cc.x + t4v[j4 * 4 + 0]; lk[j4 * 4 + 0] = v > 0.0f ? v : 0.02f * v;
    v = a.y + cc.y + t4v[j4 * 4 + 1]; lk[j4 * 4 + 1] = v > 0.0f ? v : 0.02f * v;
    v = a.z + cc.z + t4v[j4 * 4 + 2]; lk[j4 * 4 + 2] = v > 0.0f ? v : 0.02f * v;
    v = a.w + cc.w + t4v[j4 * 4 + 3]; lk[j4 * 4 + 3] = v > 0.0f ? v : 0.02f * v;
  }
  float pw[8] = {0, 0, 0, 0, 0, 0, 0, 0};
#pragma unroll
  for (int j = 0; j < 16; j++) {
    float4 u = *(const float4*)(kq + j * 8);
    float4 v = *(const float4*)(kq + j * 8 + 4);
    float l = lk[j];
    pw[0] += l * u.x; pw[1] += l * u.y; pw[2] += l * u.z; pw[3] += l * u.w;
    pw[4] += l * v.x; pw[5] += l * v.y; pw[6] += l * v.z; pw[7] += l * v.w;
  }
#pragma unroll
  for (int w = 0; w < 8; w++) {  // reduce over the 4 s-lanes
    pw[w] += __shfl_xor(pw[w], 1);
    pw[w] += __shfl_xor(pw[w], 2);
  }
  float2 o;
  o.x = fmaxf(pw[2 * s] + k5_b[2 * s], 0.0f);
  o.y = fmaxf(pw[2 * s + 1] + k5_b[2 * s + 1], 0.0f);
  *(float2*)(kv + pos * 512 + b * 8 + 2 * s) = o;
}

// Aggregation + gc GEMM, one block (512 thr) per partition, 2 edge-slots.
__global__ __launch_bounds__(512, 2) void k_agg(
    const unsigned short* __restrict__ xh, const float* __restrict__ kv,
    const int2* __restrict__ pe2, const int* __restrict__ part_start,
    const float* __restrict__ gc_w, const float* __restrict__ gc_b,
    float* __restrict__ yg) {
  __shared__ float accS[64 * 128]; // fp32 [b][w-half k], XOR-swizzled (32 KB)
  __shared__ float gcS[64 * 256];  // gc_w staged (64 KB)
  int p = blockIdx.x, t = threadIdx.x;
  int slot = t >> 8;
  int ts = t & 255;
  int s = ts & 3, b = ts >> 2;
  for (int i4 = t; i4 < 4096; i4 += 512)
    ((float4*)gcS)[i4] = ((const float4*)gc_w)[i4];
  float acc[64];   // acc[w*8 + j], f = s*8 + j
#pragma unroll
  for (int j = 0; j < 64; j++) acc[j] = 0.0f;
  int s0 = part_start[p], s1 = part_start[p + 1];
  int idx = s0 + slot;
  int r = (idx < s1) ? pe2[idx].y : 0;
  for (; idx < s1; idx += 2) {
    int rn = (idx + 2 < s1) ? pe2[idx + 2].y : 0;
    const float4* kvp = (const float4*)(kv + idx * 512 + b * 8);
    float4 ka = kvp[0], kc = kvp[1];
    int4 xw = *(const int4*)(xh + r * 2048 + b * 32 + s * 8);
    float kw[8] = {ka.x, ka.y, ka.z, ka.w, kc.x, kc.y, kc.z, kc.w};
    float xa[8];
    {
      unsigned int uu;
      uu = (unsigned int)xw.x; xa[0] = __uint_as_float(uu << 16); xa[1] = __uint_as_float(uu & 0xffff0000u);
      uu = (unsigned int)xw.y; xa[2] = __uint_as_float(uu << 16); xa[3] = __uint_as_float(uu & 0xffff0000u);
      uu = (unsigned int)xw.z; xa[4] = __uint_as_float(uu << 16); xa[5] = __uint_as_float(uu & 0xffff0000u);
      uu = (unsigned int)xw.w; xa[6] = __uint_as_float(uu << 16); xa[7] = __uint_as_float(uu & 0xffff0000u);
    }
#pragma unroll
    for (int w = 0; w < 8; w++)
#pragma unroll
      for (int j = 0; j < 8; j++) acc[w * 8 + j] += kw[w] * xa[j];
    r = rn;
  }
  // ---- slot merge + gc GEMM in two w-half phases (fp32 exact) ----
  int gq = t >> 6, be = t & 63;
  float ac[8];
#pragma unroll
  for (int i = 0; i < 8; i++) ac[i] = 0.0f;
#pragma unroll
  for (int ph = 0; ph < 2; ph++) {
    if (ph) __syncthreads();  // protect accS while phase-0 reads finish
    if (slot == 0) {
#pragma unroll
      for (int w2 = 0; w2 < 4; w2++)
#pragma unroll
        for (int j4 = 0; j4 < 2; j4++) {
          int khalf4 = w2 * 8 + s * 2 + j4;
          int phys4 = (khalf4 & 24) | ((khalf4 ^ b) & 7);
          int j = (ph * 4 + w2) * 8 + j4 * 4;
          *(float4*)(accS + b * 128 + phys4 * 4) =
              make_float4(acc[j], acc[j + 1], acc[j + 2], acc[j + 3]);
        }
    }
    __syncthreads();
    if (slot == 1) {
#pragma unroll
      for (int w2 = 0; w2 < 4; w2++)
#pragma unroll
        for (int j4 = 0; j4 < 2; j4++) {
          int khalf4 = w2 * 8 + s * 2 + j4;
          int phys4 = (khalf4 & 24) | ((khalf4 ^ b) & 7);
          int j = (ph * 4 + w2) * 8 + j4 * 4;
          float4* ptr = (float4*)(accS + b * 128 + phys4 * 4);
          float4 o = *ptr;
          o.x += acc[j]; o.y += acc[j + 1]; o.z += acc[j + 2]; o.w += acc[j + 3];
          *ptr = o;
        }
    }
    __syncthreads();
    for (int k4h = 0; k4h < 32; k4h++) {
      int phys4 = (k4h & 24) | ((k4h ^ be) & 7);
      float4 av = *(const float4*)(accS + be * 128 + phys4 * 4);
      int w2 = k4h >> 3;
      int k4g = (ph * 4 + w2) * 8 + (k4h & 7);  // global float4 col
#pragma unroll
      for (int i = 0; i < 8; i++) {
        float4 wv = *(const float4*)(gcS + (gq * 8 + i) * 256 + k4g * 4);
        ac[i] += av.x * wv.x + av.y * wv.y + av.z * wv.z + av.w * wv.w;
      }
    }
  }
  float* yp = yg + be * 16384 + p * 64 + gq * 8;
#pragma unroll
  for (int i = 0; i < 8; i++)
    yp[i] = fmaxf(ac[i] + gc_b[gq * 8 + i], 0.0f);
}

// r0 GEMM partials: grid 256 = (kc 64) x (rhq 4). Bid mapping puts the 4
// rhq blocks of one kc on ONE XCD (bid%8 = kc&7) so the shared yg slice is
// L2-resident. Block computes 64b x 64rh over K=256 in 4 LDS sub-tiles,
// accumulating in registers; part[kc][b][rh] is 4 MB (was 16).
__global__ __launch_bounds__(256) void k_r0(const float* __restrict__ yg,
    const float* __restrict__ r0_w, float* __restrict__ part) {
  __shared__ float ygs[64 * 68];   // [k][b], stride 68
  __shared__ float wts[64 * 68];   // [k][rh_local], stride 68
  int bid = blockIdx.x, t = threadIdx.x;
  int kc = ((bid >> 5) << 3) | (bid & 7);   // kc & 7 == bid & 7 -> same XCD
  int rhq = (bid >> 3) & 3;
  int rh0 = rhq * 64;
  int lane = t & 63, wv = t >> 6;
  int b4 = lane & 15;                 // b-group: b = b4*4 + i
  int r4 = (lane >> 4) | (wv << 2);   // rh-group: rh = rh0 + r4*4 + j
  float acc[4][4];
#pragma unroll
  for (int i = 0; i < 4; i++)
#pragma unroll
    for (int j = 0; j < 4; j++) acc[i][j] = 0.0f;
  for (int sub = 0; sub < 4; sub++) {
    int k0 = kc * 256 + sub * 64;
    if (sub) __syncthreads();   // LDS reuse across sub-tiles
    {
      int rl = t >> 2, kq = t & 3;
      const float* src = r0_w + (rh0 + rl) * 16384 + k0 + kq * 16;
#pragma unroll
      for (int u = 0; u < 4; u++) {
        float4 v = *(const float4*)(src + u * 4);
        int kk = kq * 16 + u * 4;
        wts[(kk + 0) * 68 + rl] = v.x;
        wts[(kk + 1) * 68 + rl] = v.y;
        wts[(kk + 2) * 68 + rl] = v.z;
        wts[(kk + 3) * 68 + rl] = v.w;
      }
    }
    {
      int b = t >> 2, kq = t & 3;
      const float* src = yg + b * 16384 + k0 + kq * 16;
#pragma unroll
      for (int u = 0; u < 4; u++) {
        float4 v = *(const float4*)(src + u * 4);
        int kk = kq * 16 + u * 4;
        ygs[(kk + 0) * 68 + b] = v.x;
        ygs[(kk + 1) * 68 + b] = v.y;
        ygs[(kk + 2) * 68 + b] = v.z;
        ygs[(kk + 3) * 68 + b] = v.w;
      }
    }
    __syncthreads();
    const float* yp = ygs + b4 * 4;
    const float* wp = wts + r4 * 4;
#pragma unroll 4
    for (int k = 0; k < 64; k++) {
      float4 yv = *(const float4*)(yp + k * 68);
      float4 wr = *(const float4*)(wp + k * 68);
      float ya[4] = {yv.x, yv.y, yv.z, yv.w};
      float wa[4] = {wr.x, wr.y, wr.z, wr.w};
#pragma unroll
      for (int i = 0; i < 4; i++)
#pragma unroll
        for (int j = 0; j < 4; j++) acc[i][j] += ya[i] * wa[j];
    }
  }
  float* pb = part + kc * 16384 + rh0 + r4 * 4;
#pragma unroll
  for (int i = 0; i < 4; i++) {
    *(float4*)(pb + (b4 * 4 + i) * 256) =
        make_float4(acc[i][0], acc[i][1], acc[i][2], acc[i][3]);
  }
}

// Reduce partials: grid 256 = (kq 4) x (oq 64). hbuf[o] += sum of 16 slabs.
__global__ __launch_bounds__(256) void k_r0red(const float* __restrict__ part,
    float* __restrict__ hbuf) {
  int blk = blockIdx.x;
  int oq = blk & 63, kq = blk >> 6;
  int o = oq * 256 + threadIdx.x;
  float s = 0.0f;
  const float* pp = part + kq * 16 * 16384 + o;
#pragma unroll 8
  for (int kc = 0; kc < 16; kc++) s += pp[kc * 16384];
  atomicAdd(&hbuf[o], s);
}

// grid 256 = (bb, pq): wt for 64 p's, partial res over those p's -> res4[pq][b][g]
__global__ __launch_bounds__(256) void k_wt_res(const float* __restrict__ hbuf,
    const float* __restrict__ r3_w, const float* __restrict__ r3_b,
    const float* __restrict__ yg, float* __restrict__ res4) {
  __shared__ float hs[256];
  __shared__ float wts[64];
  __shared__ float red[256];
  int blk = blockIdx.x;
  int bb = blk >> 2, pq = blk & 3;
  int t = threadIdx.x;
  float hv = hbuf[bb * 256 + t];
  hs[t] = hv > 0.0f ? hv : 0.01f * hv;
  __syncthreads();
  int pl = t >> 2, c = t & 3;
  int pp = pq * 64 + pl;
  const float4* wrow = (const float4*)(r3_w + pp * 256 + c * 64);
  const float4* h4 = (const float4*)(hs) + c * 16;
  float a = 0.0f;
#pragma unroll
  for (int j = 0; j < 16; j++) {
    float4 w4 = wrow[j], hh = h4[j];
    a += hh.x * w4.x + hh.y * w4.y + hh.z * w4.z + hh.w * w4.w;
  }
  a += __shfl_xor(a, 1);
  a += __shfl_xor(a, 2);
  if (c == 0) wts[pl] = fmaxf(a + r3_b[pp], 0.0f);
  __syncthreads();
  int g = t & 63, ch = t >> 6;
  float r = 0.0f;
  const float* ygp = yg + bb * 16384 + pq * 4096 + g;
#pragma unroll
  for (int pi = 0; pi < 16; pi++) {
    int pl2 = ch * 16 + pi;
    r += wts[pl2] * ygp[pl2 * 64];
  }
  red[t] = r;
  __syncthreads();
  if (t < 64)
    res4[pq * 4096 + bb * 64 + t] = red[t] + red[t + 64] + red[t + 128] + red[t + 192];
}

// z = elu([sum(res4), x2] @ l1_w^T + l1_b); out = z @ l3_w^T + l3_b
__global__ __launch_bounds__(128) void k_final(const float* __restrict__ res4,
    const float* __restrict__ x2, const float* __restrict__ l1_w,
    const float* __restrict__ l1_b, const float* __restrict__ l3_w,
    const float* __restrict__ l3_b, float* __restrict__ out) {
  __shared__ float zs[128];
  int bb = blockIdx.x, t = threadIdx.x;
  float acc = l1_b[t];
  const float* wrow = l1_w + t * 72;
  const float* rr = res4 + bb * 64;
#pragma unroll 8
  for (int j = 0; j < 64; j++) {
    float rv = rr[j] + rr[4096 + j] + rr[8192 + j] + rr[12288 + j];
    acc += rv * wrow[j];
  }
  const float* xr = x2 + bb * 8;
#pragma unroll
  for (int j = 0; j < 8; j++) acc += xr[j] * wrow[64 + j];
  zs[t] = acc > 0.0f ? acc : expm1f(acc);
  __syncthreads();
  if (t < 9) {
    float o = l3_b[t];
    const float* w3 = l3_w + t * 128;
    for (int j = 0; j < 128; j++) o += zs[j] * w3[j];
    out[bb * 9 + t] = o;
  }
}

extern "C" void kernel_launch(void* const* d_in, const int* in_sizes, int n_in,
                              void* d_out, int out_size, void* d_ws, size_t ws_size,
                              hipStream_t stream) {
  (void)in_sizes; (void)n_in; (void)out_size; (void)ws_size;
  const float* x1     = (const float*)d_in[0];
  const float* x2     = (const float*)d_in[1];
  const float* conv_w = (const float*)d_in[2];
  const float* conv_b = (const float*)d_in[3];
  const float* k1_w   = (const float*)d_in[4];
  const float* k1_b   = (const float*)d_in[5];
  const float* k2_w   = (const float*)d_in[6];
  const float* k3_w   = (const float*)d_in[7];
  const float* k4_w   = (const float*)d_in[8];
  const float* k5_w   = (const float*)d_in[9];
  const float* k5_b   = (const float*)d_in[10];
  const float* gc_w   = (const float*)d_in[11];
  const float* gc_b   = (const float*)d_in[12];
  const float* r0_w   = (const float*)d_in[13];
  const float* r1_w   = (const float*)d_in[14];
  const float* r1_b   = (const float*)d_in[15];
  const float* r2_w   = (const float*)d_in[16];
  const float* r3_w   = (const float*)d_in[17];
  const float* r3_b   = (const float*)d_in[18];
  const float* l1_w   = (const float*)d_in[19];
  const float* l1_b   = (const float*)d_in[20];
  const float* l3_w   = (const float*)d_in[21];
  const float* l3_b   = (const float*)d_in[22];
  const float* ef     = (const float*)d_in[23];
  const float* linc   = (const float*)d_in[24];
  const float* rinc   = (const float*)d_in[25];
  const float* cap    = (const float*)d_in[26];
  const int*   pidx   = (const int*)d_in[27];
  float* out = (float*)d_out;

  float* ws   = (float*)d_ws;
  float* xbuf = ws + X_OFF;
  unsigned short* t4h = (unsigned short*)(ws + T4_OFF);              // 2M bf16
  unsigned short* xh  = (unsigned short*)(ws + T4_OFF + N_*B_*H_/2); // 1M bf16
  float* t3   = ws + T3_OFF;
  float* kb   = ws + KB_OFF;
  float* kv   = ws + KW_OFF;
  float* yg   = ws + YG_OFF;
  float* hbuf = ws + HB_OFF;
  float* res4 = ws + RES_OFF;
  float* part = ws + X_OFF;   // 4 MB, aliases x fp32 (dead after k_prep)
  int* ib = (int*)(ws + INT_OFF);
  int* lidx = ib;
  int* ridx = ib + 4096;
  int* part_start = ib + 8192;
  int2* pe2 = (int2*)(ib + 8704);      // 4096 int2 = 8192 ints
  float* capv = ws + INT_OFF + 16896;  // 256 floats after pe2

  hipLaunchKernelGGL(k_dc, dim3(3585), dim3(256), 0, stream,
                     linc, rinc, lidx, ridx, x1, conv_w, conv_b, xbuf, xh,
                     cap, r2_w, capv);
  hipLaunchKernelGGL(k_prep, dim3(1857), dim3(256), 0, stream,
                     xbuf, pidx, k3_w, k4_w, x2, k2_w, ef, k1_w, k1_b,
                     r1_w, r1_b, capv, lidx, ridx,
                     t4h, t3, kb, hbuf, part_start, pe2);
  hipLaunchKernelGGL(k_kern, dim3(4096), dim3(256), 0, stream,
                     kb, t3, t4h, k5_w, k5_b, pe2, kv);
  hipLaunchKernelGGL(k_agg, dim3(256), dim3(512), 0, stream,
                     xh, kv, pe2, part_start, gc_w, gc_b, yg);
  hipLaunchKernelGGL(k_r0, dim3(256), dim3(256), 0, stream, yg, r0_w, part);
  hipLaunchKernelGGL(k_r0red, dim3(256), dim3(256), 0, stream, part, hbuf);
  hipLaunchKernelGGL(k_wt_res, dim3(256), dim3(256), 0, stream, hbuf, r3_w, r3_b, yg, res4);
  hipLaunchKernelGGL(k_final, dim3(64), dim3(128), 0, stream,
                     res4, x2, l1_w, l1_b, l3_w, l3_b, out);
}